// Round 6
// baseline (286.980 us; speedup 1.0000x reference)
//
#include <hip/hip_runtime.h>

#define NTOK 2048
#define NEXP 8
#define TOPK 2
#define NITEM 4096   // NTOK*TOPK
#define DIM 1024
#define HID 2816
#define CAP 4096
#define LDP 72       // fallback-path padded LDS stride (u16)

typedef unsigned short u16;
typedef __bf16 bf16x8 __attribute__((ext_vector_type(8)));
typedef float f32x4 __attribute__((ext_vector_type(4)));

__device__ __forceinline__ u16 f2bf(float f) {
  unsigned u = __float_as_uint(f);
  return (u16)((u + 0x7FFFu + ((u >> 16) & 1u)) >> 16);
}
__device__ __forceinline__ unsigned pk2(float a, float b) {
  return (unsigned)f2bf(a) | ((unsigned)f2bf(b) << 16);
}
__device__ __forceinline__ void async16(const void* g, void* l) {
  __builtin_amdgcn_global_load_lds(
      (const __attribute__((address_space(1))) unsigned int*)g,
      (__attribute__((address_space(3))) unsigned int*)l, 16, 0, 0);
}
// Fragment pointer into a [rows][32] u16 LDS tile (64 B rows), XOR-swizzled:
// element col c of row r lives at byte (r*64) + ((c*2) ^ ((r&3)<<4)).
// Source columns are pre-swizzled at global_load_lds time to match.
__device__ __forceinline__ const bf16x8* fragp32(const u16* base, int row, int kg) {
  int byte = (row << 6) + (((kg << 4) ^ ((row & 3) << 4)));
  return (const bf16x8*)((const char*)base + byte);
}

__global__ void zero8(int* counts) {
  if (threadIdx.x < NEXP) counts[threadIdx.x] = 0;
}

__global__ void bucket(const int* __restrict__ ei, int* counts, int* lists) {
  int item = blockIdx.x * 256 + threadIdx.x;
  if (item < NITEM) {
    int e = ei[item] & 7;
    int pos = atomicAdd(&counts[e], 1);
    if (pos < CAP) lists[e * CAP + pos] = item;
  }
}

// generic f32 -> bf16 convert, 8 elems/thread
__global__ __launch_bounds__(256) void cvt8(const float* __restrict__ src,
                                            u16* __restrict__ dst, int n8) {
  int i = blockIdx.x * 256 + threadIdx.x;
  if (i >= n8) return;
  float4 v0 = *(const float4*)(src + (size_t)i * 8);
  float4 v1 = *(const float4*)(src + (size_t)i * 8 + 4);
  uint4 u;
  u.x = pk2(v0.x, v0.y); u.y = pk2(v0.z, v0.w);
  u.z = pk2(v1.x, v1.y); u.w = pk2(v1.z, v1.w);
  *(uint4*)(dst + (size_t)i * 8) = u;
}

// w2 [E][H][D] f32 -> w2t [E][D][H] bf16, 64x64 LDS tile transpose
__global__ __launch_bounds__(256) void tw2(const float* __restrict__ w2, u16* __restrict__ w2t) {
  __shared__ float tile[64][65];
  const int e = blockIdx.z;
  const int h0 = blockIdx.y * 64;
  const int d0 = blockIdx.x * 64;
  const int tid = threadIdx.x;
  const int r = tid >> 4, c = (tid & 15) * 4;
  const float* src = w2 + (size_t)e * HID * DIM;
#pragma unroll
  for (int p = 0; p < 4; ++p) {
    float4 v = *(const float4*)(src + (size_t)(h0 + p * 16 + r) * DIM + d0 + c);
    tile[p * 16 + r][c] = v.x;
    tile[p * 16 + r][c + 1] = v.y;
    tile[p * 16 + r][c + 2] = v.z;
    tile[p * 16 + r][c + 3] = v.w;
  }
  __syncthreads();
  u16* dst = w2t + (size_t)e * DIM * HID;
#pragma unroll
  for (int p = 0; p < 4; ++p) {
    int dd = p * 16 + r;
    uint2 pkv;
    pkv.x = pk2(tile[c][dd], tile[c + 1][dd]);
    pkv.y = pk2(tile[c + 2][dd], tile[c + 3][dd]);
    *(uint2*)(dst + (size_t)(d0 + dd) * HID + h0 + c) = pkv;
  }
}

// ---------------- Path A: 2-phase double-buffered bf16 GEMMs (BK=32) ----------------

// GEMM1: X_e[128 items x DIM] * {w1b,w3b}[e]^T[128 h x DIM] -> G = silu(x1)*x3 (bf16)
__global__ __launch_bounds__(256, 2) void gemm1A(
    const u16* __restrict__ xb, const u16* __restrict__ w1b,
    const u16* __restrict__ w3b, const int* __restrict__ counts,
    const int* __restrict__ lists, u16* __restrict__ G) {
  __shared__ __align__(16) u16 As[2][128 * 32];
  __shared__ __align__(16) u16 B1s[2][128 * 32];
  __shared__ __align__(16) u16 B3s[2][128 * 32];
  __shared__ int toks[128];

  const int e = blockIdx.z;
  int cnt = counts[e];
  if ((unsigned)cnt > CAP) cnt = 0;
  const int m0 = blockIdx.y * 128;
  if (m0 >= cnt) return;
  const int n0 = blockIdx.x * 128;
  const int tid = threadIdx.x;

  if (tid < 128) {
    int r = m0 + tid;
    int it = lists[e * CAP + (r < cnt ? r : 0)];
    toks[tid] = ((unsigned)it < NITEM) ? it : 0;
  }
  __syncthreads();

  const int lane = tid & 63;
  const int wr = ((tid >> 7) & 1) * 64;
  const int wc = ((tid >> 6) & 1) * 64;
  const int lr = lane & 15;
  const int kg = lane >> 4;

  // staging: pass p covers rows p*64..p*64+63; thread handles row prow, 16B slot pc
  const int prow = tid >> 2;                     // 0..63
  const int scol = ((tid & 3) ^ (prow & 3)) * 8; // pre-swizzled source column

  const u16* xs0 = xb + (size_t)(toks[prow] >> 1) * DIM + scol;        // item -> token
  const u16* xs1 = xb + (size_t)(toks[64 + prow] >> 1) * DIM + scol;
  const u16* b1a = w1b + ((size_t)e * HID + n0 + prow) * DIM + scol;
  const u16* b1b = b1a + (size_t)64 * DIM;
  const u16* b3a = w3b + ((size_t)e * HID + n0 + prow) * DIM + scol;
  const u16* b3b = b3a + (size_t)64 * DIM;

  const int doff = tid * 16;  // linear dest byte offset within a pass

  f32x4 acc1[4][4] = {};
  f32x4 acc3[4][4] = {};

#define STG1(buf, k)                                             \
  {                                                              \
    char* aD = (char*)As[buf] + doff;                            \
    char* d1 = (char*)B1s[buf] + doff;                           \
    char* d3 = (char*)B3s[buf] + doff;                           \
    async16(xs0 + (k), aD);                                      \
    async16(xs1 + (k), aD + 4096);                               \
    async16(b1a + (k), d1);                                      \
    async16(b1b + (k), d1 + 4096);                               \
    async16(b3a + (k), d3);                                      \
    async16(b3b + (k), d3 + 4096);                               \
  }

  STG1(0, 0);
  __syncthreads();

  int cur = 0;
  for (int k0 = 0; k0 < DIM; k0 += 32) {
    const int nk = k0 + 32;
    if (nk < DIM) STG1(cur ^ 1, nk);
    const u16* Ab = As[cur];
    const u16* B1b_ = B1s[cur];
    const u16* B3b_ = B3s[cur];
    bf16x8 a[4];
#pragma unroll
    for (int m = 0; m < 4; ++m) a[m] = *fragp32(Ab, wr + m * 16 + lr, kg);
#pragma unroll
    for (int n = 0; n < 4; ++n) {
      bf16x8 b1 = *fragp32(B1b_, wc + n * 16 + lr, kg);
      bf16x8 b3 = *fragp32(B3b_, wc + n * 16 + lr, kg);
#pragma unroll
      for (int m = 0; m < 4; ++m) {
        acc1[m][n] = __builtin_amdgcn_mfma_f32_16x16x32_bf16(a[m], b1, acc1[m][n], 0, 0, 0);
        acc3[m][n] = __builtin_amdgcn_mfma_f32_16x16x32_bf16(a[m], b3, acc3[m][n], 0, 0, 0);
      }
    }
    __syncthreads();  // drains next-tile vmcnt AFTER compute + barrier
    cur ^= 1;
  }
#undef STG1

#pragma unroll
  for (int m = 0; m < 4; ++m) {
#pragma unroll
    for (int r = 0; r < 4; ++r) {
      const int row = wr + m * 16 + kg * 4 + r;
      if (m0 + row < cnt) {
        const int it = toks[row];
        u16* gp = G + (size_t)it * HID + n0 + wc + lr;
#pragma unroll
        for (int n = 0; n < 4; ++n) {
          float v1 = acc1[m][n][r];
          float v3 = acc3[m][n][r];
          float s = v1 / (1.f + __expf(-v1)) * v3;
          gp[n * 16] = f2bf(s);
        }
      }
    }
  }
}

// GEMM2: out[item][d] = G[item][:] . w2t[e][d][:]  — 128x128 tile, 2-phase, BK=32
__global__ __launch_bounds__(256, 2) void gemm2A(
    const u16* __restrict__ G, const u16* __restrict__ w2t,
    const int* __restrict__ counts, const int* __restrict__ lists,
    float* __restrict__ out) {
  __shared__ __align__(16) u16 As[2][128 * 32];
  __shared__ __align__(16) u16 Bs[2][128 * 32];
  __shared__ int toks[128];

  const int e = blockIdx.z;
  int cnt = counts[e];
  if ((unsigned)cnt > CAP) cnt = 0;
  const int m0 = blockIdx.y * 128;
  if (m0 >= cnt) return;
  const int n0 = blockIdx.x * 128;
  const int tid = threadIdx.x;

  if (tid < 128) {
    int r = m0 + tid;
    int it = lists[e * CAP + (r < cnt ? r : 0)];
    toks[tid] = ((unsigned)it < NITEM) ? it : 0;
  }
  __syncthreads();

  const int lane = tid & 63;
  const int wr = ((tid >> 7) & 1) * 64;
  const int wc = ((tid >> 6) & 1) * 64;
  const int lr = lane & 15;
  const int kg = lane >> 4;

  const int prow = tid >> 2;
  const int scol = ((tid & 3) ^ (prow & 3)) * 8;

  const u16* as0 = G + (size_t)toks[prow] * HID + scol;
  const u16* as1 = G + (size_t)toks[64 + prow] * HID + scol;
  const u16* bs0 = w2t + ((size_t)e * DIM + n0 + prow) * HID + scol;
  const u16* bs1 = bs0 + (size_t)64 * HID;

  const int doff = tid * 16;

  f32x4 acc[4][4] = {};

#define STG2(buf, k)                       \
  {                                        \
    char* aD = (char*)As[buf] + doff;      \
    char* bD = (char*)Bs[buf] + doff;      \
    async16(as0 + (k), aD);                \
    async16(as1 + (k), aD + 4096);         \
    async16(bs0 + (k), bD);                \
    async16(bs1 + (k), bD + 4096);         \
  }

  STG2(0, 0);
  __syncthreads();

  int cur = 0;
  for (int k0 = 0; k0 < HID; k0 += 32) {
    const int nk = k0 + 32;
    if (nk < HID) STG2(cur ^ 1, nk);
    const u16* Ab = As[cur];
    const u16* Bb = Bs[cur];
    bf16x8 a[4], b[4];
#pragma unroll
    for (int m = 0; m < 4; ++m) a[m] = *fragp32(Ab, wr + m * 16 + lr, kg);
#pragma unroll
    for (int n = 0; n < 4; ++n) b[n] = *fragp32(Bb, wc + n * 16 + lr, kg);
#pragma unroll
    for (int n = 0; n < 4; ++n)
#pragma unroll
      for (int m = 0; m < 4; ++m)
        acc[m][n] = __builtin_amdgcn_mfma_f32_16x16x32_bf16(a[m], b[n], acc[m][n], 0, 0, 0);
    __syncthreads();
    cur ^= 1;
  }
#undef STG2

#pragma unroll
  for (int m = 0; m < 4; ++m) {
#pragma unroll
    for (int r = 0; r < 4; ++r) {
      const int row = wr + m * 16 + kg * 4 + r;
      if (m0 + row < cnt) {
        const int it = toks[row];
        float* op = out + (size_t)it * DIM + n0 + wc + lr;
#pragma unroll
        for (int n = 0; n < 4; ++n)
          op[n * 16] = acc[m][n][r];
      }
    }
  }
}

// ---------------- Path B (fallback, small workspace): round-2 kernels ----------------

__global__ __launch_bounds__(256, 2) void gemm1B(
    const float* __restrict__ x, const float* __restrict__ w1,
    const float* __restrict__ w3, const int* __restrict__ counts,
    const int* __restrict__ lists, u16* __restrict__ G) {
  __shared__ __align__(16) u16 As[128 * LDP];
  __shared__ __align__(16) u16 B1s[128 * LDP];
  __shared__ __align__(16) u16 B3s[128 * LDP];
  __shared__ int toks[128];

  const int e = blockIdx.z;
  int cnt = counts[e];
  if ((unsigned)cnt > CAP) cnt = 0;
  const int m0 = blockIdx.y * 128;
  if (m0 >= cnt) return;
  const int n0 = blockIdx.x * 128;
  const int tid = threadIdx.x;

  if (tid < 128) {
    int r = m0 + tid;
    int it = lists[e * CAP + (r < cnt ? r : 0)];
    toks[tid] = ((unsigned)it < NITEM) ? it : 0;
  }
  __syncthreads();

  const int lane = tid & 63;
  const int wr = ((tid >> 7) & 1) * 64;
  const int wc = ((tid >> 6) & 1) * 64;
  const int lr = lane & 15;
  const int kg = lane >> 4;
  const int arow = tid >> 3;
  const int c8 = (tid & 7) * 8;

  const float* xsrc[4];
#pragma unroll
  for (int p = 0; p < 4; ++p)
    xsrc[p] = x + (size_t)(toks[p * 32 + arow] >> 1) * DIM + c8;
  const float* w1p = w1 + ((size_t)e * HID + n0 + arow) * DIM + c8;
  const float* w3p = w3 + ((size_t)e * HID + n0 + arow) * DIM + c8;

  f32x4 acc1[4][4] = {};
  f32x4 acc3[4][4] = {};

  for (int k0 = 0; k0 < DIM; k0 += 64) {
#pragma unroll
    for (int p = 0; p < 4; ++p) {
      float4 v0 = *(const float4*)(xsrc[p] + k0);
      float4 v1 = *(const float4*)(xsrc[p] + k0 + 4);
      uint4 u;
      u.x = pk2(v0.x, v0.y); u.y = pk2(v0.z, v0.w);
      u.z = pk2(v1.x, v1.y); u.w = pk2(v1.z, v1.w);
      *(uint4*)&As[(p * 32 + arow) * LDP + c8] = u;
    }
#pragma unroll
    for (int p = 0; p < 4; ++p) {
      float4 v0 = *(const float4*)(w1p + (size_t)(p * 32) * DIM + k0);
      float4 v1 = *(const float4*)(w1p + (size_t)(p * 32) * DIM + k0 + 4);
      uint4 u;
      u.x = pk2(v0.x, v0.y); u.y = pk2(v0.z, v0.w);
      u.z = pk2(v1.x, v1.y); u.w = pk2(v1.z, v1.w);
      *(uint4*)&B1s[(p * 32 + arow) * LDP + c8] = u;
      v0 = *(const float4*)(w3p + (size_t)(p * 32) * DIM + k0);
      v1 = *(const float4*)(w3p + (size_t)(p * 32) * DIM + k0 + 4);
      u.x = pk2(v0.x, v0.y); u.y = pk2(v0.z, v0.w);
      u.z = pk2(v1.x, v1.y); u.w = pk2(v1.z, v1.w);
      *(uint4*)&B3s[(p * 32 + arow) * LDP + c8] = u;
    }
    __syncthreads();
#pragma unroll
    for (int kk = 0; kk < 2; ++kk) {
      const int ko = kk * 32 + kg * 8;
      bf16x8 a[4];
#pragma unroll
      for (int m = 0; m < 4; ++m)
        a[m] = *(const bf16x8*)&As[(wr + m * 16 + lr) * LDP + ko];
#pragma unroll
      for (int n = 0; n < 4; ++n) {
        bf16x8 b1 = *(const bf16x8*)&B1s[(wc + n * 16 + lr) * LDP + ko];
        bf16x8 b3 = *(const bf16x8*)&B3s[(wc + n * 16 + lr) * LDP + ko];
#pragma unroll
        for (int m = 0; m < 4; ++m) {
          acc1[m][n] = __builtin_amdgcn_mfma_f32_16x16x32_bf16(a[m], b1, acc1[m][n], 0, 0, 0);
          acc3[m][n] = __builtin_amdgcn_mfma_f32_16x16x32_bf16(a[m], b3, acc3[m][n], 0, 0, 0);
        }
      }
    }
    __syncthreads();
  }

#pragma unroll
  for (int m = 0; m < 4; ++m) {
#pragma unroll
    for (int r = 0; r < 4; ++r) {
      const int row = wr + m * 16 + kg * 4 + r;
      if (m0 + row < cnt) {
        const int it = toks[row];
        u16* gp = G + (size_t)it * HID + n0 + wc + lr;
#pragma unroll
        for (int n = 0; n < 4; ++n) {
          float v1 = acc1[m][n][r];
          float v3 = acc3[m][n][r];
          float s = v1 / (1.f + __expf(-v1)) * v3;
          gp[n * 16] = f2bf(s);
        }
      }
    }
  }
}

__global__ __launch_bounds__(256, 2) void gemm2B(
    const u16* __restrict__ G, const float* __restrict__ w2,
    const int* __restrict__ counts, const int* __restrict__ lists,
    float* __restrict__ out) {
  __shared__ __align__(16) u16 As[128 * LDP];
  __shared__ __align__(16) u16 Bs[128 * LDP];
  __shared__ int toks[128];

  const int e = blockIdx.z;
  int cnt = counts[e];
  if ((unsigned)cnt > CAP) cnt = 0;
  const int m0 = blockIdx.y * 128;
  if (m0 >= cnt) return;
  const int n0 = blockIdx.x * 128;
  const int tid = threadIdx.x;

  if (tid < 128) {
    int r = m0 + tid;
    int it = lists[e * CAP + (r < cnt ? r : 0)];
    toks[tid] = ((unsigned)it < NITEM) ? it : 0;
  }
  __syncthreads();

  const int lane = tid & 63;
  const int wr = ((tid >> 7) & 1) * 64;
  const int wc = ((tid >> 6) & 1) * 64;
  const int lr = lane & 15;
  const int kg = lane >> 4;
  const int arow = tid >> 3;
  const int c8 = (tid & 7) * 8;
  const int brow = tid >> 5;
  const int d4 = (tid & 31) * 4;

  const u16* asrc[4];
#pragma unroll
  for (int p = 0; p < 4; ++p)
    asrc[p] = G + (size_t)toks[p * 32 + arow] * HID + c8;
  const float* bsrc = w2 + ((size_t)e * HID) * DIM + n0 + d4;

  f32x4 acc[4][4] = {};

  for (int k0 = 0; k0 < HID; k0 += 64) {
#pragma unroll
    for (int p = 0; p < 4; ++p) {
      uint4 u = *(const uint4*)(asrc[p] + k0);
      *(uint4*)&As[(p * 32 + arow) * LDP + c8] = u;
    }
#pragma unroll
    for (int p = 0; p < 8; ++p) {
      const int hl = p * 8 + brow;
      float4 v = *(const float4*)(bsrc + (size_t)(k0 + hl) * DIM);
      Bs[(d4 + 0) * LDP + hl] = f2bf(v.x);
      Bs[(d4 + 1) * LDP + hl] = f2bf(v.y);
      Bs[(d4 + 2) * LDP + hl] = f2bf(v.z);
      Bs[(d4 + 3) * LDP + hl] = f2bf(v.w);
    }
    __syncthreads();
#pragma unroll
    for (int kk = 0; kk < 2; ++kk) {
      const int ko = kk * 32 + kg * 8;
      bf16x8 a[4];
#pragma unroll
      for (int m = 0; m < 4; ++m)
        a[m] = *(const bf16x8*)&As[(wr + m * 16 + lr) * LDP + ko];
#pragma unroll
      for (int n = 0; n < 4; ++n) {
        bf16x8 b = *(const bf16x8*)&Bs[(wc + n * 16 + lr) * LDP + ko];
#pragma unroll
        for (int m = 0; m < 4; ++m)
          acc[m][n] = __builtin_amdgcn_mfma_f32_16x16x32_bf16(a[m], b, acc[m][n], 0, 0, 0);
      }
    }
    __syncthreads();
  }

#pragma unroll
  for (int m = 0; m < 4; ++m) {
#pragma unroll
    for (int r = 0; r < 4; ++r) {
      const int row = wr + m * 16 + kg * 4 + r;
      if (m0 + row < cnt) {
        const int it = toks[row];
        float* op = out + (size_t)it * DIM + n0 + wc + lr;
#pragma unroll
        for (int n = 0; n < 4; ++n)
          op[n * 16] = acc[m][n][r];
      }
    }
  }
}

extern "C" void kernel_launch(void* const* d_in, const int* in_sizes, int n_in,
                              void* d_out, int out_size, void* d_ws, size_t ws_size,
                              hipStream_t stream) {
  (void)in_sizes; (void)n_in; (void)out_size;
  const float* x  = (const float*)d_in[0];
  const int*   ei = (const int*)d_in[1];
  const float* w1 = (const float*)d_in[2];
  const float* w2 = (const float*)d_in[3];
  const float* w3 = (const float*)d_in[4];
  float* out = (float*)d_out;

  char* ws = (char*)d_ws;

  // Path A layout: G | xb | w1b | w3b | w2t | counts | lists
  const size_t oG = 0;
  const size_t oXB = 23068672u;
  const size_t oW1 = oXB + 4194304u;
  const size_t oW3 = oW1 + 46137344u;
  const size_t oW2T = oW3 + 46137344u;
  const size_t oCNT = oW2T + 46137344u;
  const size_t oLST = oCNT + 64u;
  const size_t needA = oLST + 131072u;  // ~165.8 MB

  if (ws_size >= needA) {
    u16* G      = (u16*)(ws + oG);
    u16* xb     = (u16*)(ws + oXB);
    u16* w1b    = (u16*)(ws + oW1);
    u16* w3b    = (u16*)(ws + oW3);
    u16* w2t    = (u16*)(ws + oW2T);
    int* counts = (int*)(ws + oCNT);
    int* lists  = (int*)(ws + oLST);

    zero8<<<1, 64, 0, stream>>>(counts);
    bucket<<<NITEM / 256, 256, 0, stream>>>(ei, counts, lists);
    cvt8<<<(NTOK * DIM / 8) / 256, 256, 0, stream>>>(x, xb, NTOK * DIM / 8);
    cvt8<<<(NEXP * HID * DIM / 8) / 256, 256, 0, stream>>>(w1, w1b, NEXP * HID * DIM / 8);
    cvt8<<<(NEXP * HID * DIM / 8) / 256, 256, 0, stream>>>(w3, w3b, NEXP * HID * DIM / 8);
    tw2<<<dim3(DIM / 64, HID / 64, NEXP), 256, 0, stream>>>(w2, w2t);
    gemm1A<<<dim3(HID / 128, CAP / 128, NEXP), 256, 0, stream>>>(xb, w1b, w3b, counts, lists, G);
    gemm2A<<<dim3(DIM / 128, CAP / 128, NEXP), 256, 0, stream>>>(G, w2t, counts, lists, out);
  } else {
    // fallback: compact workspace, on-the-fly conversion (round-2 path)
    u16* G      = (u16*)ws;
    int* counts = (int*)(ws + 23068672u);
    int* lists  = (int*)(ws + 23068736u);

    zero8<<<1, 64, 0, stream>>>(counts);
    bucket<<<NITEM / 256, 256, 0, stream>>>(ei, counts, lists);
    gemm1B<<<dim3(HID / 128, CAP / 128, NEXP), 256, 0, stream>>>(x, w1, w3, counts, lists, G);
    gemm2B<<<dim3(DIM / 128, CAP / 128, NEXP), 256, 0, stream>>>(G, w2, counts, lists, out);
  }
}

// Round 7
// 231.193 us; speedup vs baseline: 1.2413x; 1.2413x over previous
//
#include <hip/hip_runtime.h>

#define NTOK 2048
#define NEXP 8
#define TOPK 2
#define NITEM 4096   // NTOK*TOPK
#define DIM 1024
#define HID 2816
#define CAP 4096
#define LDP 72       // fallback-path padded LDS stride (u16)

typedef unsigned short u16;
typedef __bf16 bf16x8 __attribute__((ext_vector_type(8)));
typedef float f32x4 __attribute__((ext_vector_type(4)));

__device__ __forceinline__ u16 f2bf(float f) {
  unsigned u = __float_as_uint(f);
  return (u16)((u + 0x7FFFu + ((u >> 16) & 1u)) >> 16);
}
__device__ __forceinline__ unsigned pk2(float a, float b) {
  return (unsigned)f2bf(a) | ((unsigned)f2bf(b) << 16);
}
__device__ __forceinline__ void async16(const void* g, void* l) {
  __builtin_amdgcn_global_load_lds(
      (const __attribute__((address_space(1))) unsigned int*)g,
      (__attribute__((address_space(3))) unsigned int*)l, 16, 0, 0);
}
// 128B-row tile fragment ptr (BK=64), XOR swizzle (row&7)<<4 — R4-verified 0 conflicts.
__device__ __forceinline__ const bf16x8* fragpA(const u16* base, int row, int ko) {
  int byte = ((row << 7) + (ko << 1)) ^ ((row & 7) << 4);
  return (const bf16x8*)((const char*)base + byte);
}
// 64B-row tile fragment ptr (BK=32), XOR swizzle ((row>>1)&3)<<4 — 2-way (free).
__device__ __forceinline__ const bf16x8* fragpB(const u16* base, int row, int kg) {
  int byte = (row << 6) + ((kg << 4) ^ (((row >> 1) & 3) << 4));
  return (const bf16x8*)((const char*)base + byte);
}
// pack 8 f32 -> 8 bf16 (RNE via native cast) and store 16B
__device__ __forceinline__ void cvst8(const float4& a, const float4& b, void* dst) {
  union { __bf16 h[8]; uint4 q; } u;
  u.h[0] = (__bf16)a.x; u.h[1] = (__bf16)a.y; u.h[2] = (__bf16)a.z; u.h[3] = (__bf16)a.w;
  u.h[4] = (__bf16)b.x; u.h[5] = (__bf16)b.y; u.h[6] = (__bf16)b.z; u.h[7] = (__bf16)b.w;
  *(uint4*)dst = u.q;
}

__global__ void zero8(int* counts) {
  if (threadIdx.x < NEXP) counts[threadIdx.x] = 0;
}

__global__ void bucket(const int* __restrict__ ei, int* counts, int* lists) {
  int item = blockIdx.x * 256 + threadIdx.x;
  if (item < NITEM) {
    int e = ei[item] & 7;
    int pos = atomicAdd(&counts[e], 1);
    if (pos < CAP) lists[e * CAP + pos] = item;
  }
}

// f32 -> bf16 convert, 8 elems/thread
__global__ __launch_bounds__(256) void cvt8(const float* __restrict__ src,
                                            u16* __restrict__ dst, int n8) {
  int i = blockIdx.x * 256 + threadIdx.x;
  if (i >= n8) return;
  float4 v0 = *(const float4*)(src + (size_t)i * 8);
  float4 v1 = *(const float4*)(src + (size_t)i * 8 + 4);
  uint4 u;
  u.x = pk2(v0.x, v0.y); u.y = pk2(v0.z, v0.w);
  u.z = pk2(v1.x, v1.y); u.w = pk2(v1.z, v1.w);
  *(uint4*)(dst + (size_t)i * 8) = u;
}

// w2 [E][H][D] f32 -> w2t [E][D][H] bf16, 64x64 LDS tile transpose
__global__ __launch_bounds__(256) void tw2(const float* __restrict__ w2, u16* __restrict__ w2t) {
  __shared__ float tile[64][65];
  const int e = blockIdx.z;
  const int h0 = blockIdx.y * 64;
  const int d0 = blockIdx.x * 64;
  const int tid = threadIdx.x;
  const int r = tid >> 4, c = (tid & 15) * 4;
  const float* src = w2 + (size_t)e * HID * DIM;
#pragma unroll
  for (int p = 0; p < 4; ++p) {
    float4 v = *(const float4*)(src + (size_t)(h0 + p * 16 + r) * DIM + d0 + c);
    tile[p * 16 + r][c] = v.x;
    tile[p * 16 + r][c + 1] = v.y;
    tile[p * 16 + r][c + 2] = v.z;
    tile[p * 16 + r][c + 3] = v.w;
  }
  __syncthreads();
  u16* dst = w2t + (size_t)e * DIM * HID;
#pragma unroll
  for (int p = 0; p < 4; ++p) {
    int dd = p * 16 + r;
    uint2 pkv;
    pkv.x = pk2(tile[c][dd], tile[c + 1][dd]);
    pkv.y = pk2(tile[c + 2][dd], tile[c + 3][dd]);
    *(uint2*)(dst + (size_t)(d0 + dd) * HID + h0 + c) = pkv;
  }
}

// ---------------- Path A ----------------

// GEMM1 fused-convert: A (bf16 x) via global_load_lds; B1/B3 read f32, converted in-reg,
// ds_write swizzled. 128x128 tile, BK=32, double-buffered 2-phase.
__global__ __launch_bounds__(256, 2) void gemm1F(
    const u16* __restrict__ xb, const float* __restrict__ w1,
    const float* __restrict__ w3, const int* __restrict__ counts,
    const int* __restrict__ lists, u16* __restrict__ G) {
  __shared__ __align__(16) u16 As[2][128 * 32];
  __shared__ __align__(16) u16 B1s[2][128 * 32];
  __shared__ __align__(16) u16 B3s[2][128 * 32];
  __shared__ int toks[128];

  const int e = blockIdx.z;
  int cnt = counts[e];
  if ((unsigned)cnt > CAP) cnt = 0;
  const int m0 = blockIdx.y * 128;
  if (m0 >= cnt) return;
  const int n0 = blockIdx.x * 128;
  const int tid = threadIdx.x;

  if (tid < 128) {
    int r = m0 + tid;
    int it = lists[e * CAP + (r < cnt ? r : 0)];
    toks[tid] = ((unsigned)it < NITEM) ? it : 0;
  }
  __syncthreads();

  const int lane = tid & 63;
  const int wr = ((tid >> 7) & 1) * 64;
  const int wc = ((tid >> 6) & 1) * 64;
  const int lr = lane & 15;
  const int kg = lane >> 4;

  // A staging (global_load_lds, linear dest): thread t -> rows prow, prow+64; chunk t&3.
  const int prow = tid >> 2;
  const int ascol = ((tid & 3) ^ ((prow >> 1) & 3)) * 8;  // pre-swizzled source col
  const u16* xs0 = xb + (size_t)(toks[prow] >> 1) * DIM + ascol;
  const u16* xs1 = xb + (size_t)(toks[64 + prow] >> 1) * DIM + ascol;

  // B staging (reg): thread t -> row br = t>>1, f32 col base cb = (t&1)*16
  const int br = tid >> 1;
  const int cb = (tid & 1) * 16;
  const float* w1p = w1 + ((size_t)e * HID + n0 + br) * DIM + cb;
  const float* w3p = w3 + ((size_t)e * HID + n0 + br) * DIM + cb;
  const int bswz = (((br >> 1) & 3) << 4);
  const int bby0 = (br << 6) + ((((tid & 1) * 2 + 0) << 4) ^ bswz);
  const int bby1 = (br << 6) + ((((tid & 1) * 2 + 1) << 4) ^ bswz);

  float4 r1[4], r3[4];

  f32x4 acc1[4][4] = {};
  f32x4 acc3[4][4] = {};

#define LOADB(k)                                             \
  {                                                          \
    _Pragma("unroll") for (int i = 0; i < 4; ++i) {          \
      r1[i] = *(const float4*)(w1p + (k) + 4 * i);           \
      r3[i] = *(const float4*)(w3p + (k) + 4 * i);           \
    }                                                        \
  }
#define STGA(buf, k)                                         \
  {                                                          \
    char* aD = (char*)As[buf] + tid * 16;                    \
    async16(xs0 + (k), aD);                                  \
    async16(xs1 + (k), aD + 4096);                           \
  }
#define WRITEB(buf)                                          \
  {                                                          \
    char* d1 = (char*)B1s[buf];                              \
    char* d3 = (char*)B3s[buf];                              \
    cvst8(r1[0], r1[1], d1 + bby0);                          \
    cvst8(r1[2], r1[3], d1 + bby1);                          \
    cvst8(r3[0], r3[1], d3 + bby0);                          \
    cvst8(r3[2], r3[3], d3 + bby1);                          \
  }

  LOADB(0);
  STGA(0, 0);
  WRITEB(0);
  LOADB(32);
  __syncthreads();

  int cur = 0;
  for (int k0 = 0; k0 < DIM; k0 += 32) {
    const int nk = k0 + 32;
    if (nk < DIM) {
      STGA(cur ^ 1, nk);
      WRITEB(cur ^ 1);           // regs hold tile nk
      if (nk + 32 < DIM) LOADB(nk + 32);
    }
    const u16* Ab = As[cur];
    const u16* B1b = B1s[cur];
    const u16* B3b = B3s[cur];
    bf16x8 a[4];
#pragma unroll
    for (int m = 0; m < 4; ++m) a[m] = *fragpB(Ab, wr + m * 16 + lr, kg);
#pragma unroll
    for (int n = 0; n < 4; ++n) {
      bf16x8 b1 = *fragpB(B1b, wc + n * 16 + lr, kg);
      bf16x8 b3 = *fragpB(B3b, wc + n * 16 + lr, kg);
#pragma unroll
      for (int m = 0; m < 4; ++m) {
        acc1[m][n] = __builtin_amdgcn_mfma_f32_16x16x32_bf16(a[m], b1, acc1[m][n], 0, 0, 0);
        acc3[m][n] = __builtin_amdgcn_mfma_f32_16x16x32_bf16(a[m], b3, acc3[m][n], 0, 0, 0);
      }
    }
    __syncthreads();
    cur ^= 1;
  }
#undef LOADB
#undef STGA
#undef WRITEB

#pragma unroll
  for (int m = 0; m < 4; ++m) {
#pragma unroll
    for (int r = 0; r < 4; ++r) {
      const int row = wr + m * 16 + kg * 4 + r;
      if (m0 + row < cnt) {
        const int it = toks[row];
        u16* gp = G + (size_t)it * HID + n0 + wc + lr;
#pragma unroll
        for (int n = 0; n < 4; ++n) {
          float v1 = acc1[m][n][r];
          float v3 = acc3[m][n][r];
          float s = v1 / (1.f + __expf(-v1)) * v3;
          gp[n * 16] = f2bf(s);
        }
      }
    }
  }
}

// GEMM2: out[item][d] = G[item][:] . w2t[e][d][:] — 128x64 tile, BK=64, dbuf 2-phase,
// both operands global_load_lds with R4 conflict-free swizzle.
__global__ __launch_bounds__(256, 3) void gemm2F(
    const u16* __restrict__ G, const u16* __restrict__ w2t,
    const int* __restrict__ counts, const int* __restrict__ lists,
    float* __restrict__ out) {
  __shared__ __align__(16) u16 As[2][128 * 64];  // 16 KB each
  __shared__ __align__(16) u16 Bs[2][64 * 64];   // 8 KB each
  __shared__ int toks[128];

  const int e = blockIdx.z;
  int cnt = counts[e];
  if ((unsigned)cnt > CAP) cnt = 0;
  const int m0 = blockIdx.y * 128;
  if (m0 >= cnt) return;
  const int n0 = blockIdx.x * 64;
  const int tid = threadIdx.x;

  if (tid < 128) {
    int r = m0 + tid;
    int it = lists[e * CAP + (r < cnt ? r : 0)];
    toks[tid] = ((unsigned)it < NITEM) ? it : 0;
  }
  __syncthreads();

  const int lane = tid & 63;
  const int wid = tid >> 6;
  const int wr = (wid >> 1) * 64;   // {0,64}
  const int wc = (wid & 1) * 32;    // {0,32}
  const int lr = lane & 15;
  const int kg = lane >> 4;

  const int srow = tid >> 3;                       // 0..31
  const int scol = ((tid & 7) ^ (srow & 7)) * 8;   // pre-swizzled source col (128B rows)

  const u16* as0 = G + (size_t)toks[srow] * HID + scol;
  const u16* as1 = G + (size_t)toks[32 + srow] * HID + scol;
  const u16* as2 = G + (size_t)toks[64 + srow] * HID + scol;
  const u16* as3 = G + (size_t)toks[96 + srow] * HID + scol;
  const u16* bs0 = w2t + ((size_t)e * DIM + n0 + srow) * HID + scol;
  const u16* bs1 = bs0 + (size_t)32 * HID;

  f32x4 acc[4][2] = {};

#define STG2(buf, k)                          \
  {                                           \
    char* aD = (char*)As[buf] + tid * 16;     \
    char* bD = (char*)Bs[buf] + tid * 16;     \
    async16(as0 + (k), aD);                   \
    async16(as1 + (k), aD + 4096);            \
    async16(as2 + (k), aD + 8192);            \
    async16(as3 + (k), aD + 12288);           \
    async16(bs0 + (k), bD);                   \
    async16(bs1 + (k), bD + 4096);            \
  }

  STG2(0, 0);
  __syncthreads();

  int cur = 0;
  for (int k0 = 0; k0 < HID; k0 += 64) {
    if (k0 + 64 < HID) STG2(cur ^ 1, k0 + 64);
    const u16* Ab = As[cur];
    const u16* Bb = Bs[cur];
#pragma unroll
    for (int kk = 0; kk < 2; ++kk) {
      const int ko = kk * 32 + kg * 8;
      bf16x8 a[4], b[2];
#pragma unroll
      for (int m = 0; m < 4; ++m) a[m] = *fragpA(Ab, wr + m * 16 + lr, ko);
#pragma unroll
      for (int n = 0; n < 2; ++n) b[n] = *fragpA(Bb, wc + n * 16 + lr, ko);
#pragma unroll
      for (int n = 0; n < 2; ++n)
#pragma unroll
        for (int m = 0; m < 4; ++m)
          acc[m][n] = __builtin_amdgcn_mfma_f32_16x16x32_bf16(a[m], b[n], acc[m][n], 0, 0, 0);
    }
    __syncthreads();
    cur ^= 1;
  }
#undef STG2

#pragma unroll
  for (int m = 0; m < 4; ++m) {
#pragma unroll
    for (int r = 0; r < 4; ++r) {
      const int row = wr + m * 16 + kg * 4 + r;
      if (m0 + row < cnt) {
        const int it = toks[row];
        float* op = out + (size_t)it * DIM + n0 + wc + lr;
#pragma unroll
        for (int n = 0; n < 2; ++n)
          op[n * 16] = acc[m][n][r];
      }
    }
  }
}

// ---------------- Path B (fallback, small workspace): round-2 kernels ----------------

__global__ __launch_bounds__(256, 2) void gemm1B(
    const float* __restrict__ x, const float* __restrict__ w1,
    const float* __restrict__ w3, const int* __restrict__ counts,
    const int* __restrict__ lists, u16* __restrict__ G) {
  __shared__ __align__(16) u16 As[128 * LDP];
  __shared__ __align__(16) u16 B1s[128 * LDP];
  __shared__ __align__(16) u16 B3s[128 * LDP];
  __shared__ int toks[128];

  const int e = blockIdx.z;
  int cnt = counts[e];
  if ((unsigned)cnt > CAP) cnt = 0;
  const int m0 = blockIdx.y * 128;
  if (m0 >= cnt) return;
  const int n0 = blockIdx.x * 128;
  const int tid = threadIdx.x;

  if (tid < 128) {
    int r = m0 + tid;
    int it = lists[e * CAP + (r < cnt ? r : 0)];
    toks[tid] = ((unsigned)it < NITEM) ? it : 0;
  }
  __syncthreads();

  const int lane = tid & 63;
  const int wr = ((tid >> 7) & 1) * 64;
  const int wc = ((tid >> 6) & 1) * 64;
  const int lr = lane & 15;
  const int kg = lane >> 4;
  const int arow = tid >> 3;
  const int c8 = (tid & 7) * 8;

  const float* xsrc[4];
#pragma unroll
  for (int p = 0; p < 4; ++p)
    xsrc[p] = x + (size_t)(toks[p * 32 + arow] >> 1) * DIM + c8;
  const float* w1p = w1 + ((size_t)e * HID + n0 + arow) * DIM + c8;
  const float* w3p = w3 + ((size_t)e * HID + n0 + arow) * DIM + c8;

  f32x4 acc1[4][4] = {};
  f32x4 acc3[4][4] = {};

  for (int k0 = 0; k0 < DIM; k0 += 64) {
#pragma unroll
    for (int p = 0; p < 4; ++p) {
      float4 v0 = *(const float4*)(xsrc[p] + k0);
      float4 v1 = *(const float4*)(xsrc[p] + k0 + 4);
      uint4 u;
      u.x = pk2(v0.x, v0.y); u.y = pk2(v0.z, v0.w);
      u.z = pk2(v1.x, v1.y); u.w = pk2(v1.z, v1.w);
      *(uint4*)&As[(p * 32 + arow) * LDP + c8] = u;
    }
#pragma unroll
    for (int p = 0; p < 4; ++p) {
      float4 v0 = *(const float4*)(w1p + (size_t)(p * 32) * DIM + k0);
      float4 v1 = *(const float4*)(w1p + (size_t)(p * 32) * DIM + k0 + 4);
      uint4 u;
      u.x = pk2(v0.x, v0.y); u.y = pk2(v0.z, v0.w);
      u.z = pk2(v1.x, v1.y); u.w = pk2(v1.z, v1.w);
      *(uint4*)&B1s[(p * 32 + arow) * LDP + c8] = u;
      v0 = *(const float4*)(w3p + (size_t)(p * 32) * DIM + k0);
      v1 = *(const float4*)(w3p + (size_t)(p * 32) * DIM + k0 + 4);
      u.x = pk2(v0.x, v0.y); u.y = pk2(v0.z, v0.w);
      u.z = pk2(v1.x, v1.y); u.w = pk2(v1.z, v1.w);
      *(uint4*)&B3s[(p * 32 + arow) * LDP + c8] = u;
    }
    __syncthreads();
#pragma unroll
    for (int kk = 0; kk < 2; ++kk) {
      const int ko = kk * 32 + kg * 8;
      bf16x8 a[4];
#pragma unroll
      for (int m = 0; m < 4; ++m)
        a[m] = *(const bf16x8*)&As[(wr + m * 16 + lr) * LDP + ko];
#pragma unroll
      for (int n = 0; n < 4; ++n) {
        bf16x8 b1 = *(const bf16x8*)&B1s[(wc + n * 16 + lr) * LDP + ko];
        bf16x8 b3 = *(const bf16x8*)&B3s[(wc + n * 16 + lr) * LDP + ko];
#pragma unroll
        for (int m = 0; m < 4; ++m) {
          acc1[m][n] = __builtin_amdgcn_mfma_f32_16x16x32_bf16(a[m], b1, acc1[m][n], 0, 0, 0);
          acc3[m][n] = __builtin_amdgcn_mfma_f32_16x16x32_bf16(a[m], b3, acc3[m][n], 0, 0, 0);
        }
      }
    }
    __syncthreads();
  }

#pragma unroll
  for (int m = 0; m < 4; ++m) {
#pragma unroll
    for (int r = 0; r < 4; ++r) {
      const int row = wr + m * 16 + kg * 4 + r;
      if (m0 + row < cnt) {
        const int it = toks[row];
        u16* gp = G + (size_t)it * HID + n0 + wc + lr;
#pragma unroll
        for (int n = 0; n < 4; ++n) {
          float v1 = acc1[m][n][r];
          float v3 = acc3[m][n][r];
          float s = v1 / (1.f + __expf(-v1)) * v3;
          gp[n * 16] = f2bf(s);
        }
      }
    }
  }
}

__global__ __launch_bounds__(256, 2) void gemm2B(
    const u16* __restrict__ G, const float* __restrict__ w2,
    const int* __restrict__ counts, const int* __restrict__ lists,
    float* __restrict__ out) {
  __shared__ __align__(16) u16 As[128 * LDP];
  __shared__ __align__(16) u16 Bs[128 * LDP];
  __shared__ int toks[128];

  const int e = blockIdx.z;
  int cnt = counts[e];
  if ((unsigned)cnt > CAP) cnt = 0;
  const int m0 = blockIdx.y * 128;
  if (m0 >= cnt) return;
  const int n0 = blockIdx.x * 128;
  const int tid = threadIdx.x;

  if (tid < 128) {
    int r = m0 + tid;
    int it = lists[e * CAP + (r < cnt ? r : 0)];
    toks[tid] = ((unsigned)it < NITEM) ? it : 0;
  }
  __syncthreads();

  const int lane = tid & 63;
  const int wr = ((tid >> 7) & 1) * 64;
  const int wc = ((tid >> 6) & 1) * 64;
  const int lr = lane & 15;
  const int kg = lane >> 4;
  const int arow = tid >> 3;
  const int c8 = (tid & 7) * 8;
  const int brow = tid >> 5;
  const int d4 = (tid & 31) * 4;

  const u16* asrc[4];
#pragma unroll
  for (int p = 0; p < 4; ++p)
    asrc[p] = G + (size_t)toks[p * 32 + arow] * HID + c8;
  const float* bsrc = w2 + ((size_t)e * HID) * DIM + n0 + d4;

  f32x4 acc[4][4] = {};

  for (int k0 = 0; k0 < HID; k0 += 64) {
#pragma unroll
    for (int p = 0; p < 4; ++p) {
      uint4 u = *(const uint4*)(asrc[p] + k0);
      *(uint4*)&As[(p * 32 + arow) * LDP + c8] = u;
    }
#pragma unroll
    for (int p = 0; p < 8; ++p) {
      const int hl = p * 8 + brow;
      float4 v = *(const float4*)(bsrc + (size_t)(k0 + hl) * DIM);
      Bs[(d4 + 0) * LDP + hl] = f2bf(v.x);
      Bs[(d4 + 1) * LDP + hl] = f2bf(v.y);
      Bs[(d4 + 2) * LDP + hl] = f2bf(v.z);
      Bs[(d4 + 3) * LDP + hl] = f2bf(v.w);
    }
    __syncthreads();
#pragma unroll
    for (int kk = 0; kk < 2; ++kk) {
      const int ko = kk * 32 + kg * 8;
      bf16x8 a[4];
#pragma unroll
      for (int m = 0; m < 4; ++m)
        a[m] = *(const bf16x8*)&As[(wr + m * 16 + lr) * LDP + ko];
#pragma unroll
      for (int n = 0; n < 4; ++n) {
        bf16x8 b = *(const bf16x8*)&Bs[(wc + n * 16 + lr) * LDP + ko];
#pragma unroll
        for (int m = 0; m < 4; ++m)
          acc[m][n] = __builtin_amdgcn_mfma_f32_16x16x32_bf16(a[m], b, acc[m][n], 0, 0, 0);
      }
    }
    __syncthreads();
  }

#pragma unroll
  for (int m = 0; m < 4; ++m) {
#pragma unroll
    for (int r = 0; r < 4; ++r) {
      const int row = wr + m * 16 + kg * 4 + r;
      if (m0 + row < cnt) {
        const int it = toks[row];
        float* op = out + (size_t)it * DIM + n0 + wc + lr;
#pragma unroll
        for (int n = 0; n < 4; ++n)
          op[n * 16] = acc[m][n][r];
      }
    }
  }
}

extern "C" void kernel_launch(void* const* d_in, const int* in_sizes, int n_in,
                              void* d_out, int out_size, void* d_ws, size_t ws_size,
                              hipStream_t stream) {
  (void)in_sizes; (void)n_in; (void)out_size;
  const float* x  = (const float*)d_in[0];
  const int*   ei = (const int*)d_in[1];
  const float* w1 = (const float*)d_in[2];
  const float* w2 = (const float*)d_in[3];
  const float* w3 = (const float*)d_in[4];
  float* out = (float*)d_out;

  char* ws = (char*)d_ws;

  // Path A layout: G | xb | w2t | counts | lists  (~73.5 MB)
  const size_t oG = 0;
  const size_t oXB = 23068672u;
  const size_t oW2T = oXB + 4194304u;
  const size_t oCNT = oW2T + 46137344u;
  const size_t oLST = oCNT + 64u;
  const size_t needA = oLST + 131072u;

  if (ws_size >= needA) {
    u16* G      = (u16*)(ws + oG);
    u16* xb     = (u16*)(ws + oXB);
    u16* w2t    = (u16*)(ws + oW2T);
    int* counts = (int*)(ws + oCNT);
    int* lists  = (int*)(ws + oLST);

    zero8<<<1, 64, 0, stream>>>(counts);
    bucket<<<NITEM / 256, 256, 0, stream>>>(ei, counts, lists);
    cvt8<<<(NTOK * DIM / 8) / 256, 256, 0, stream>>>(x, xb, NTOK * DIM / 8);
    gemm1F<<<dim3(HID / 128, CAP / 128, NEXP), 256, 0, stream>>>(xb, w1, w3, counts, lists, G);
    tw2<<<dim3(DIM / 64, HID / 64, NEXP), 256, 0, stream>>>(w2, w2t);
    gemm2F<<<dim3(DIM / 64, CAP / 128, NEXP), 256, 0, stream>>>(G, w2t, counts, lists, out);
  } else {
    // fallback: compact workspace, on-the-fly conversion (round-2 path)
    u16* G      = (u16*)ws;
    int* counts = (int*)(ws + 23068672u);
    int* lists  = (int*)(ws + 23068736u);

    zero8<<<1, 64, 0, stream>>>(counts);
    bucket<<<NITEM / 256, 256, 0, stream>>>(ei, counts, lists);
    gemm1B<<<dim3(HID / 128, CAP / 128, NEXP), 256, 0, stream>>>(x, w1, w3, counts, lists, G);
    gemm2B<<<dim3(DIM / 128, CAP / 128, NEXP), 256, 0, stream>>>(G, w2, counts, lists, out);
  }
}

// Round 8
// 220.989 us; speedup vs baseline: 1.2986x; 1.0462x over previous
//
#include <hip/hip_runtime.h>

#define NTOK 2048
#define NEXP 8
#define TOPK 2
#define NITEM 4096   // NTOK*TOPK
#define DIM 1024
#define HID 2816
#define CAP 4096
#define LDP 72       // fallback-path padded LDS stride (u16)

typedef unsigned short u16;
typedef __bf16 bf16x8 __attribute__((ext_vector_type(8)));
typedef float f32x4 __attribute__((ext_vector_type(4)));

__device__ __forceinline__ u16 f2bf(float f) {
  unsigned u = __float_as_uint(f);
  return (u16)((u + 0x7FFFu + ((u >> 16) & 1u)) >> 16);
}
__device__ __forceinline__ unsigned pk2(float a, float b) {
  return (unsigned)f2bf(a) | ((unsigned)f2bf(b) << 16);
}
__device__ __forceinline__ void async16(const void* g, void* l) {
  __builtin_amdgcn_global_load_lds(
      (const __attribute__((address_space(1))) unsigned int*)g,
      (__attribute__((address_space(3))) unsigned int*)l, 16, 0, 0);
}
// 128B-row tile fragment ptr (BK=64), XOR swizzle (row&7)<<4 — R4-verified 0 conflicts.
__device__ __forceinline__ const bf16x8* fragpA(const u16* base, int row, int ko) {
  int byte = ((row << 7) + (ko << 1)) ^ ((row & 7) << 4);
  return (const bf16x8*)((const char*)base + byte);
}
// 64B-row tile fragment ptr (BK=32), XOR swizzle ((row>>1)&3)<<4 — R7-verified 0 conflicts.
__device__ __forceinline__ const bf16x8* fragpB(const u16* base, int row, int kg) {
  int byte = (row << 6) + ((kg << 4) ^ (((row >> 1) & 3) << 4));
  return (const bf16x8*)((const char*)base + byte);
}
// pack 8 f32 -> 8 bf16 (RNE via native cast) and store 16B
__device__ __forceinline__ void cvst8(const float4& a, const float4& b, void* dst) {
  union { __bf16 h[8]; uint4 q; } u;
  u.h[0] = (__bf16)a.x; u.h[1] = (__bf16)a.y; u.h[2] = (__bf16)a.z; u.h[3] = (__bf16)a.w;
  u.h[4] = (__bf16)b.x; u.h[5] = (__bf16)b.y; u.h[6] = (__bf16)b.z; u.h[7] = (__bf16)b.w;
  *(uint4*)dst = u.q;
}

__global__ void zero8(int* counts) {
  if (threadIdx.x < NEXP) counts[threadIdx.x] = 0;
}

__global__ void bucket(const int* __restrict__ ei, int* counts, int* lists) {
  int item = blockIdx.x * 256 + threadIdx.x;
  if (item < NITEM) {
    int e = ei[item] & 7;
    int pos = atomicAdd(&counts[e], 1);
    if (pos < CAP) lists[e * CAP + pos] = item;
  }
}

// f32 -> bf16 convert, 8 elems/thread
__global__ __launch_bounds__(256) void cvt8(const float* __restrict__ src,
                                            u16* __restrict__ dst, int n8) {
  int i = blockIdx.x * 256 + threadIdx.x;
  if (i >= n8) return;
  float4 v0 = *(const float4*)(src + (size_t)i * 8);
  float4 v1 = *(const float4*)(src + (size_t)i * 8 + 4);
  uint4 u;
  u.x = pk2(v0.x, v0.y); u.y = pk2(v0.z, v0.w);
  u.z = pk2(v1.x, v1.y); u.w = pk2(v1.z, v1.w);
  *(uint4*)(dst + (size_t)i * 8) = u;
}

// w2 [E][H][D] f32 -> w2t [E][D][H] bf16, 64x64 LDS tile transpose
__global__ __launch_bounds__(256) void tw2(const float* __restrict__ w2, u16* __restrict__ w2t) {
  __shared__ float tile[64][65];
  const int e = blockIdx.z;
  const int h0 = blockIdx.y * 64;
  const int d0 = blockIdx.x * 64;
  const int tid = threadIdx.x;
  const int r = tid >> 4, c = (tid & 15) * 4;
  const float* src = w2 + (size_t)e * HID * DIM;
#pragma unroll
  for (int p = 0; p < 4; ++p) {
    float4 v = *(const float4*)(src + (size_t)(h0 + p * 16 + r) * DIM + d0 + c);
    tile[p * 16 + r][c] = v.x;
    tile[p * 16 + r][c + 1] = v.y;
    tile[p * 16 + r][c + 2] = v.z;
    tile[p * 16 + r][c + 3] = v.w;
  }
  __syncthreads();
  u16* dst = w2t + (size_t)e * DIM * HID;
#pragma unroll
  for (int p = 0; p < 4; ++p) {
    int dd = p * 16 + r;
    uint2 pkv;
    pkv.x = pk2(tile[c][dd], tile[c + 1][dd]);
    pkv.y = pk2(tile[c + 2][dd], tile[c + 3][dd]);
    *(uint2*)(dst + (size_t)(d0 + dd) * HID + h0 + c) = pkv;
  }
}

// ---------------- Path A ----------------

// GEMM1: BM=256, BN=64, BK=32 dbuf. A (bf16 x) via global_load_lds (pre-swizzled src);
// B1/B3 f32 -> reg -> bf16 cvst8 to swizzled LDS. 4 m-waves of 64x64.
__global__ __launch_bounds__(256, 2) void gemm1G(
    const u16* __restrict__ xb, const float* __restrict__ w1,
    const float* __restrict__ w3, const int* __restrict__ counts,
    const int* __restrict__ lists, u16* __restrict__ G) {
  __shared__ __align__(16) u16 As[2][256 * 32];   // 16 KB each
  __shared__ __align__(16) u16 B1s[2][64 * 32];   // 4 KB each
  __shared__ __align__(16) u16 B3s[2][64 * 32];
  __shared__ int toks[256];

  const int e = blockIdx.z;
  int cnt = counts[e];
  if ((unsigned)cnt > CAP) cnt = 0;
  const int m0 = blockIdx.y * 256;
  if (m0 >= cnt) return;
  const int n0 = blockIdx.x * 64;
  const int tid = threadIdx.x;

  {
    int r = m0 + tid;
    int it = lists[e * CAP + (r < cnt ? r : 0)];
    toks[tid] = ((unsigned)it < NITEM) ? it : 0;
  }
  __syncthreads();

  const int lane = tid & 63;
  const int wrow = (tid >> 6) * 64;   // 4 m-waves
  const int lr = lane & 15;
  const int kg = lane >> 4;

  // A staging: thread t -> rows prow+64p (p=0..3), chunk q; pre-swizzled source col.
  const int prow = tid >> 2;                       // 0..63
  const int q = tid & 3;
  const int ascol = (q ^ ((prow >> 1) & 3)) * 8;   // (row+64p) preserves (row>>1)&3
  const u16* xs[4];
#pragma unroll
  for (int p = 0; p < 4; ++p)
    xs[p] = xb + (size_t)(toks[p * 64 + prow] >> 1) * DIM + ascol;  // item -> token

  // B staging: thread t -> weight row br, f32 cols q*8..q*8+7 -> one 16B bf16 chunk.
  const int br = prow;  // 0..63
  const float* w1p = w1 + ((size_t)e * HID + n0 + br) * DIM + q * 8;
  const float* w3p = w3 + ((size_t)e * HID + n0 + br) * DIM + q * 8;
  const int bby = (br << 6) + ((q << 4) ^ (((br >> 1) & 3) << 4));

  float4 r1[2], r3[2];
  f32x4 acc1[4][4] = {};
  f32x4 acc3[4][4] = {};

#define LOADB(k)                                   \
  {                                                \
    r1[0] = *(const float4*)(w1p + (k));           \
    r1[1] = *(const float4*)(w1p + (k) + 4);       \
    r3[0] = *(const float4*)(w3p + (k));           \
    r3[1] = *(const float4*)(w3p + (k) + 4);       \
  }
#define STGA(buf, k)                               \
  {                                                \
    char* aD = (char*)As[buf] + tid * 16;          \
    async16(xs[0] + (k), aD);                      \
    async16(xs[1] + (k), aD + 4096);               \
    async16(xs[2] + (k), aD + 8192);               \
    async16(xs[3] + (k), aD + 12288);              \
  }
#define WRITEB(buf)                                \
  {                                                \
    cvst8(r1[0], r1[1], (char*)B1s[buf] + bby);    \
    cvst8(r3[0], r3[1], (char*)B3s[buf] + bby);    \
  }

  LOADB(0);
  STGA(0, 0);
  WRITEB(0);
  LOADB(32);
  __syncthreads();

  int cur = 0;
  for (int k0 = 0; k0 < DIM; k0 += 32) {
    const int nk = k0 + 32;
    if (nk < DIM) {
      STGA(cur ^ 1, nk);
      WRITEB(cur ^ 1);                 // regs hold tile nk
      if (nk + 32 < DIM) LOADB(nk + 32);
    }
    const u16* Ab = As[cur];
    const u16* B1b = B1s[cur];
    const u16* B3b = B3s[cur];
    bf16x8 a[4];
#pragma unroll
    for (int m = 0; m < 4; ++m) a[m] = *fragpB(Ab, wrow + m * 16 + lr, kg);
#pragma unroll
    for (int n = 0; n < 4; ++n) {
      bf16x8 b1 = *fragpB(B1b, n * 16 + lr, kg);
      bf16x8 b3 = *fragpB(B3b, n * 16 + lr, kg);
#pragma unroll
      for (int m = 0; m < 4; ++m) {
        acc1[m][n] = __builtin_amdgcn_mfma_f32_16x16x32_bf16(a[m], b1, acc1[m][n], 0, 0, 0);
        acc3[m][n] = __builtin_amdgcn_mfma_f32_16x16x32_bf16(a[m], b3, acc3[m][n], 0, 0, 0);
      }
    }
    __syncthreads();
    cur ^= 1;
  }
#undef LOADB
#undef STGA
#undef WRITEB

#pragma unroll
  for (int m = 0; m < 4; ++m) {
#pragma unroll
    for (int r = 0; r < 4; ++r) {
      const int row = wrow + m * 16 + kg * 4 + r;
      if (m0 + row < cnt) {
        const int it = toks[row];
        u16* gp = G + (size_t)it * HID + n0 + lr;
#pragma unroll
        for (int n = 0; n < 4; ++n) {
          float v1 = acc1[m][n][r];
          float v3 = acc3[m][n][r];
          float s = v1 / (1.f + __expf(-v1)) * v3;
          gp[n * 16] = f2bf(s);
        }
      }
    }
  }
}

// GEMM2: out[item][d] = G[item][:] . w2t[e][d][:] — 128x64 tile, BK=64, dbuf 2-phase,
// both operands global_load_lds with R4 conflict-free swizzle.
__global__ __launch_bounds__(256, 3) void gemm2F(
    const u16* __restrict__ G, const u16* __restrict__ w2t,
    const int* __restrict__ counts, const int* __restrict__ lists,
    float* __restrict__ out) {
  __shared__ __align__(16) u16 As[2][128 * 64];  // 16 KB each
  __shared__ __align__(16) u16 Bs[2][64 * 64];   // 8 KB each
  __shared__ int toks[128];

  const int e = blockIdx.z;
  int cnt = counts[e];
  if ((unsigned)cnt > CAP) cnt = 0;
  const int m0 = blockIdx.y * 128;
  if (m0 >= cnt) return;
  const int n0 = blockIdx.x * 64;
  const int tid = threadIdx.x;

  if (tid < 128) {
    int r = m0 + tid;
    int it = lists[e * CAP + (r < cnt ? r : 0)];
    toks[tid] = ((unsigned)it < NITEM) ? it : 0;
  }
  __syncthreads();

  const int lane = tid & 63;
  const int wid = tid >> 6;
  const int wr = (wid >> 1) * 64;   // {0,64}
  const int wc = (wid & 1) * 32;    // {0,32}
  const int lr = lane & 15;
  const int kg = lane >> 4;

  const int srow = tid >> 3;                       // 0..31
  const int scol = ((tid & 7) ^ (srow & 7)) * 8;   // pre-swizzled source col (128B rows)

  const u16* as0 = G + (size_t)toks[srow] * HID + scol;
  const u16* as1 = G + (size_t)toks[32 + srow] * HID + scol;
  const u16* as2 = G + (size_t)toks[64 + srow] * HID + scol;
  const u16* as3 = G + (size_t)toks[96 + srow] * HID + scol;
  const u16* bs0 = w2t + ((size_t)e * DIM + n0 + srow) * HID + scol;
  const u16* bs1 = bs0 + (size_t)32 * HID;

  f32x4 acc[4][2] = {};

#define STG2(buf, k)                          \
  {                                           \
    char* aD = (char*)As[buf] + tid * 16;     \
    char* bD = (char*)Bs[buf] + tid * 16;     \
    async16(as0 + (k), aD);                   \
    async16(as1 + (k), aD + 4096);            \
    async16(as2 + (k), aD + 8192);            \
    async16(as3 + (k), aD + 12288);           \
    async16(bs0 + (k), bD);                   \
    async16(bs1 + (k), bD + 4096);            \
  }

  STG2(0, 0);
  __syncthreads();

  int cur = 0;
  for (int k0 = 0; k0 < HID; k0 += 64) {
    if (k0 + 64 < HID) STG2(cur ^ 1, k0 + 64);
    const u16* Ab = As[cur];
    const u16* Bb = Bs[cur];
#pragma unroll
    for (int kk = 0; kk < 2; ++kk) {
      const int ko = kk * 32 + kg * 8;
      bf16x8 a[4], b[2];
#pragma unroll
      for (int m = 0; m < 4; ++m) a[m] = *fragpA(Ab, wr + m * 16 + lr, ko);
#pragma unroll
      for (int n = 0; n < 2; ++n) b[n] = *fragpA(Bb, wc + n * 16 + lr, ko);
#pragma unroll
      for (int n = 0; n < 2; ++n)
#pragma unroll
        for (int m = 0; m < 4; ++m)
          acc[m][n] = __builtin_amdgcn_mfma_f32_16x16x32_bf16(a[m], b[n], acc[m][n], 0, 0, 0);
    }
    __syncthreads();
    cur ^= 1;
  }
#undef STG2

#pragma unroll
  for (int m = 0; m < 4; ++m) {
#pragma unroll
    for (int r = 0; r < 4; ++r) {
      const int row = wr + m * 16 + kg * 4 + r;
      if (m0 + row < cnt) {
        const int it = toks[row];
        float* op = out + (size_t)it * DIM + n0 + wc + lr;
#pragma unroll
        for (int n = 0; n < 2; ++n)
          op[n * 16] = acc[m][n][r];
      }
    }
  }
}

// ---------------- Path B (fallback, small workspace): round-2 kernels ----------------

__global__ __launch_bounds__(256, 2) void gemm1B(
    const float* __restrict__ x, const float* __restrict__ w1,
    const float* __restrict__ w3, const int* __restrict__ counts,
    const int* __restrict__ lists, u16* __restrict__ G) {
  __shared__ __align__(16) u16 As[128 * LDP];
  __shared__ __align__(16) u16 B1s[128 * LDP];
  __shared__ __align__(16) u16 B3s[128 * LDP];
  __shared__ int toks[128];

  const int e = blockIdx.z;
  int cnt = counts[e];
  if ((unsigned)cnt > CAP) cnt = 0;
  const int m0 = blockIdx.y * 128;
  if (m0 >= cnt) return;
  const int n0 = blockIdx.x * 128;
  const int tid = threadIdx.x;

  if (tid < 128) {
    int r = m0 + tid;
    int it = lists[e * CAP + (r < cnt ? r : 0)];
    toks[tid] = ((unsigned)it < NITEM) ? it : 0;
  }
  __syncthreads();

  const int lane = tid & 63;
  const int wr = ((tid >> 7) & 1) * 64;
  const int wc = ((tid >> 6) & 1) * 64;
  const int lr = lane & 15;
  const int kg = lane >> 4;
  const int arow = tid >> 3;
  const int c8 = (tid & 7) * 8;

  const float* xsrc[4];
#pragma unroll
  for (int p = 0; p < 4; ++p)
    xsrc[p] = x + (size_t)(toks[p * 32 + arow] >> 1) * DIM + c8;
  const float* w1p = w1 + ((size_t)e * HID + n0 + arow) * DIM + c8;
  const float* w3p = w3 + ((size_t)e * HID + n0 + arow) * DIM + c8;

  f32x4 acc1[4][4] = {};
  f32x4 acc3[4][4] = {};

  for (int k0 = 0; k0 < DIM; k0 += 64) {
#pragma unroll
    for (int p = 0; p < 4; ++p) {
      float4 v0 = *(const float4*)(xsrc[p] + k0);
      float4 v1 = *(const float4*)(xsrc[p] + k0 + 4);
      uint4 u;
      u.x = pk2(v0.x, v0.y); u.y = pk2(v0.z, v0.w);
      u.z = pk2(v1.x, v1.y); u.w = pk2(v1.z, v1.w);
      *(uint4*)&As[(p * 32 + arow) * LDP + c8] = u;
    }
#pragma unroll
    for (int p = 0; p < 4; ++p) {
      float4 v0 = *(const float4*)(w1p + (size_t)(p * 32) * DIM + k0);
      float4 v1 = *(const float4*)(w1p + (size_t)(p * 32) * DIM + k0 + 4);
      uint4 u;
      u.x = pk2(v0.x, v0.y); u.y = pk2(v0.z, v0.w);
      u.z = pk2(v1.x, v1.y); u.w = pk2(v1.z, v1.w);
      *(uint4*)&B1s[(p * 32 + arow) * LDP + c8] = u;
      v0 = *(const float4*)(w3p + (size_t)(p * 32) * DIM + k0);
      v1 = *(const float4*)(w3p + (size_t)(p * 32) * DIM + k0 + 4);
      u.x = pk2(v0.x, v0.y); u.y = pk2(v0.z, v0.w);
      u.z = pk2(v1.x, v1.y); u.w = pk2(v1.z, v1.w);
      *(uint4*)&B3s[(p * 32 + arow) * LDP + c8] = u;
    }
    __syncthreads();
#pragma unroll
    for (int kk = 0; kk < 2; ++kk) {
      const int ko = kk * 32 + kg * 8;
      bf16x8 a[4];
#pragma unroll
      for (int m = 0; m < 4; ++m)
        a[m] = *(const bf16x8*)&As[(wr + m * 16 + lr) * LDP + ko];
#pragma unroll
      for (int n = 0; n < 4; ++n) {
        bf16x8 b1 = *(const bf16x8*)&B1s[(wc + n * 16 + lr) * LDP + ko];
        bf16x8 b3 = *(const bf16x8*)&B3s[(wc + n * 16 + lr) * LDP + ko];
#pragma unroll
        for (int m = 0; m < 4; ++m) {
          acc1[m][n] = __builtin_amdgcn_mfma_f32_16x16x32_bf16(a[m], b1, acc1[m][n], 0, 0, 0);
          acc3[m][n] = __builtin_amdgcn_mfma_f32_16x16x32_bf16(a[m], b3, acc3[m][n], 0, 0, 0);
        }
      }
    }
    __syncthreads();
  }

#pragma unroll
  for (int m = 0; m < 4; ++m) {
#pragma unroll
    for (int r = 0; r < 4; ++r) {
      const int row = wr + m * 16 + kg * 4 + r;
      if (m0 + row < cnt) {
        const int it = toks[row];
        u16* gp = G + (size_t)it * HID + n0 + wc + lr;
#pragma unroll
        for (int n = 0; n < 4; ++n) {
          float v1 = acc1[m][n][r];
          float v3 = acc3[m][n][r];
          float s = v1 / (1.f + __expf(-v1)) * v3;
          gp[n * 16] = f2bf(s);
        }
      }
    }
  }
}

__global__ __launch_bounds__(256, 2) void gemm2B(
    const u16* __restrict__ G, const float* __restrict__ w2,
    const int* __restrict__ counts, const int* __restrict__ lists,
    float* __restrict__ out) {
  __shared__ __align__(16) u16 As[128 * LDP];
  __shared__ __align__(16) u16 Bs[128 * LDP];
  __shared__ int toks[128];

  const int e = blockIdx.z;
  int cnt = counts[e];
  if ((unsigned)cnt > CAP) cnt = 0;
  const int m0 = blockIdx.y * 128;
  if (m0 >= cnt) return;
  const int n0 = blockIdx.x * 128;
  const int tid = threadIdx.x;

  if (tid < 128) {
    int r = m0 + tid;
    int it = lists[e * CAP + (r < cnt ? r : 0)];
    toks[tid] = ((unsigned)it < NITEM) ? it : 0;
  }
  __syncthreads();

  const int lane = tid & 63;
  const int wr = ((tid >> 7) & 1) * 64;
  const int wc = ((tid >> 6) & 1) * 64;
  const int lr = lane & 15;
  const int kg = lane >> 4;
  const int arow = tid >> 3;
  const int c8 = (tid & 7) * 8;
  const int brow = tid >> 5;
  const int d4 = (tid & 31) * 4;

  const u16* asrc[4];
#pragma unroll
  for (int p = 0; p < 4; ++p)
    asrc[p] = G + (size_t)toks[p * 32 + arow] * HID + c8;
  const float* bsrc = w2 + ((size_t)e * HID) * DIM + n0 + d4;

  f32x4 acc[4][4] = {};

  for (int k0 = 0; k0 < HID; k0 += 64) {
#pragma unroll
    for (int p = 0; p < 4; ++p) {
      uint4 u = *(const uint4*)(asrc[p] + k0);
      *(uint4*)&As[(p * 32 + arow) * LDP + c8] = u;
    }
#pragma unroll
    for (int p = 0; p < 8; ++p) {
      const int hl = p * 8 + brow;
      float4 v = *(const float4*)(bsrc + (size_t)(k0 + hl) * DIM);
      Bs[(d4 + 0) * LDP + hl] = f2bf(v.x);
      Bs[(d4 + 1) * LDP + hl] = f2bf(v.y);
      Bs[(d4 + 2) * LDP + hl] = f2bf(v.z);
      Bs[(d4 + 3) * LDP + hl] = f2bf(v.w);
    }
    __syncthreads();
#pragma unroll
    for (int kk = 0; kk < 2; ++kk) {
      const int ko = kk * 32 + kg * 8;
      bf16x8 a[4];
#pragma unroll
      for (int m = 0; m < 4; ++m)
        a[m] = *(const bf16x8*)&As[(wr + m * 16 + lr) * LDP + ko];
#pragma unroll
      for (int n = 0; n < 4; ++n) {
        bf16x8 b = *(const bf16x8*)&Bs[(wc + n * 16 + lr) * LDP + ko];
#pragma unroll
        for (int m = 0; m < 4; ++m)
          acc[m][n] = __builtin_amdgcn_mfma_f32_16x16x32_bf16(a[m], b, acc[m][n], 0, 0, 0);
      }
    }
    __syncthreads();
  }

#pragma unroll
  for (int m = 0; m < 4; ++m) {
#pragma unroll
    for (int r = 0; r < 4; ++r) {
      const int row = wr + m * 16 + kg * 4 + r;
      if (m0 + row < cnt) {
        const int it = toks[row];
        float* op = out + (size_t)it * DIM + n0 + wc + lr;
#pragma unroll
        for (int n = 0; n < 4; ++n)
          op[n * 16] = acc[m][n][r];
      }
    }
  }
}

extern "C" void kernel_launch(void* const* d_in, const int* in_sizes, int n_in,
                              void* d_out, int out_size, void* d_ws, size_t ws_size,
                              hipStream_t stream) {
  (void)in_sizes; (void)n_in; (void)out_size;
  const float* x  = (const float*)d_in[0];
  const int*   ei = (const int*)d_in[1];
  const float* w1 = (const float*)d_in[2];
  const float* w2 = (const float*)d_in[3];
  const float* w3 = (const float*)d_in[4];
  float* out = (float*)d_out;

  char* ws = (char*)d_ws;

  // Path A layout: G | xb | w2t | counts | lists  (~73.5 MB)
  const size_t oG = 0;
  const size_t oXB = 23068672u;
  const size_t oW2T = oXB + 4194304u;
  const size_t oCNT = oW2T + 46137344u;
  const size_t oLST = oCNT + 64u;
  const size_t needA = oLST + 131072u;

  if (ws_size >= needA) {
    u16* G      = (u16*)(ws + oG);
    u16* xb     = (u16*)(ws + oXB);
    u16* w2t    = (u16*)(ws + oW2T);
    int* counts = (int*)(ws + oCNT);
    int* lists  = (int*)(ws + oLST);

    zero8<<<1, 64, 0, stream>>>(counts);
    bucket<<<NITEM / 256, 256, 0, stream>>>(ei, counts, lists);
    cvt8<<<(NTOK * DIM / 8) / 256, 256, 0, stream>>>(x, xb, NTOK * DIM / 8);
    gemm1G<<<dim3(HID / 64, CAP / 256, NEXP), 256, 0, stream>>>(xb, w1, w3, counts, lists, G);
    tw2<<<dim3(DIM / 64, HID / 64, NEXP), 256, 0, stream>>>(w2, w2t);
    gemm2F<<<dim3(DIM / 64, CAP / 128, NEXP), 256, 0, stream>>>(G, w2t, counts, lists, out);
  } else {
    // fallback: compact workspace, on-the-fly conversion (round-2 path)
    u16* G      = (u16*)ws;
    int* counts = (int*)(ws + 23068672u);
    int* lists  = (int*)(ws + 23068736u);

    zero8<<<1, 64, 0, stream>>>(counts);
    bucket<<<NITEM / 256, 256, 0, stream>>>(ei, counts, lists);
    gemm1B<<<dim3(HID / 128, CAP / 128, NEXP), 256, 0, stream>>>(x, w1, w3, counts, lists, G);
    gemm2B<<<dim3(DIM / 128, CAP / 128, NEXP), 256, 0, stream>>>(G, w2, counts, lists, out);
  }
}

// Round 9
// 211.384 us; speedup vs baseline: 1.3576x; 1.0454x over previous
//
#include <hip/hip_runtime.h>

#define NTOK 2048
#define NEXP 8
#define TOPK 2
#define NITEM 4096   // NTOK*TOPK
#define DIM 1024
#define HID 2816
#define CAP 4096
#define LDP 72       // fallback-path padded LDS stride (u16)

typedef unsigned short u16;
typedef __bf16 bf16x8 __attribute__((ext_vector_type(8)));
typedef float f32x4 __attribute__((ext_vector_type(4)));

__device__ __forceinline__ u16 f2bf(float f) {
  unsigned u = __float_as_uint(f);
  return (u16)((u + 0x7FFFu + ((u >> 16) & 1u)) >> 16);
}
__device__ __forceinline__ unsigned pk2(float a, float b) {
  return (unsigned)f2bf(a) | ((unsigned)f2bf(b) << 16);
}
__device__ __forceinline__ void async16(const void* g, void* l) {
  __builtin_amdgcn_global_load_lds(
      (const __attribute__((address_space(1))) unsigned int*)g,
      (__attribute__((address_space(3))) unsigned int*)l, 16, 0, 0);
}
// 128B-row tile fragment ptr (BK=64), XOR swizzle (row&7)<<4 — R4-verified 0 conflicts.
__device__ __forceinline__ const bf16x8* fragpA(const u16* base, int row, int ko) {
  int byte = ((row << 7) + (ko << 1)) ^ ((row & 7) << 4);
  return (const bf16x8*)((const char*)base + byte);
}
// 64B-row tile fragment ptr (BK=32), XOR swizzle ((row>>1)&3)<<4 — R7/R8-verified 0 conflicts.
__device__ __forceinline__ const bf16x8* fragpB(const u16* base, int row, int kg) {
  int byte = (row << 6) + ((kg << 4) ^ (((row >> 1) & 3) << 4));
  return (const bf16x8*)((const char*)base + byte);
}
// pack 8 f32 -> 8 bf16 (RNE via native cast) and store 16B
__device__ __forceinline__ void cvst8(const float4& a, const float4& b, void* dst) {
  union { __bf16 h[8]; uint4 q; } u;
  u.h[0] = (__bf16)a.x; u.h[1] = (__bf16)a.y; u.h[2] = (__bf16)a.z; u.h[3] = (__bf16)a.w;
  u.h[4] = (__bf16)b.x; u.h[5] = (__bf16)b.y; u.h[6] = (__bf16)b.z; u.h[7] = (__bf16)b.w;
  *(uint4*)dst = u.q;
}

__global__ void zero8(int* counts) {
  if (threadIdx.x < NEXP) counts[threadIdx.x] = 0;
}

__global__ void bucket(const int* __restrict__ ei, int* counts, int* lists) {
  int item = blockIdx.x * 256 + threadIdx.x;
  if (item < NITEM) {
    int e = ei[item] & 7;
    int pos = atomicAdd(&counts[e], 1);
    if (pos < CAP) lists[e * CAP + pos] = item;
  }
}

// f32 -> bf16 convert, 8 elems/thread
__global__ __launch_bounds__(256) void cvt8(const float* __restrict__ src,
                                            u16* __restrict__ dst, int n8) {
  int i = blockIdx.x * 256 + threadIdx.x;
  if (i >= n8) return;
  float4 v0 = *(const float4*)(src + (size_t)i * 8);
  float4 v1 = *(const float4*)(src + (size_t)i * 8 + 4);
  uint4 u;
  u.x = pk2(v0.x, v0.y); u.y = pk2(v0.z, v0.w);
  u.z = pk2(v1.x, v1.y); u.w = pk2(v1.z, v1.w);
  *(uint4*)(dst + (size_t)i * 8) = u;
}

// w2 [E][H][D] f32 -> w2t [E][D][H] bf16, 64x64 LDS tile transpose
__global__ __launch_bounds__(256) void tw2(const float* __restrict__ w2, u16* __restrict__ w2t) {
  __shared__ float tile[64][65];
  const int e = blockIdx.z;
  const int h0 = blockIdx.y * 64;
  const int d0 = blockIdx.x * 64;
  const int tid = threadIdx.x;
  const int r = tid >> 4, c = (tid & 15) * 4;
  const float* src = w2 + (size_t)e * HID * DIM;
#pragma unroll
  for (int p = 0; p < 4; ++p) {
    float4 v = *(const float4*)(src + (size_t)(h0 + p * 16 + r) * DIM + d0 + c);
    tile[p * 16 + r][c] = v.x;
    tile[p * 16 + r][c + 1] = v.y;
    tile[p * 16 + r][c + 2] = v.z;
    tile[p * 16 + r][c + 3] = v.w;
  }
  __syncthreads();
  u16* dst = w2t + (size_t)e * DIM * HID;
#pragma unroll
  for (int p = 0; p < 4; ++p) {
    int dd = p * 16 + r;
    uint2 pkv;
    pkv.x = pk2(tile[c][dd], tile[c + 1][dd]);
    pkv.y = pk2(tile[c + 2][dd], tile[c + 3][dd]);
    *(uint2*)(dst + (size_t)(d0 + dd) * HID + h0 + c) = pkv;
  }
}

// ---------------- Path A ----------------

// GEMM1: BM=256, BN=64, BK=32. Counted-vmcnt raw-barrier pipeline:
// A (bf16 x) 1-ahead via global_load_lds; B1/B3 f32 2-ahead to regs, 1-ahead cvst8->LDS.
// Main loop never drains vmcnt to 0.
__global__ __launch_bounds__(256, 2) void gemm1H(
    const u16* __restrict__ xb, const float* __restrict__ w1,
    const float* __restrict__ w3, const int* __restrict__ counts,
    const int* __restrict__ lists, u16* __restrict__ G) {
  __shared__ __align__(16) u16 As[2][256 * 32];   // 16 KB each
  __shared__ __align__(16) u16 B1s[2][64 * 32];   // 4 KB each
  __shared__ __align__(16) u16 B3s[2][64 * 32];
  __shared__ int toks[256];

  const int e = blockIdx.z;
  int cnt = counts[e];
  if ((unsigned)cnt > CAP) cnt = 0;
  const int m0 = blockIdx.y * 256;
  if (m0 >= cnt) return;
  const int n0 = blockIdx.x * 64;
  const int tid = threadIdx.x;

  {
    int r = m0 + tid;
    int it = lists[e * CAP + (r < cnt ? r : 0)];
    toks[tid] = ((unsigned)it < NITEM) ? it : 0;
  }
  __syncthreads();

  const int lane = tid & 63;
  const int wrow = (tid >> 6) * 64;   // 4 m-waves
  const int lr = lane & 15;
  const int kg = lane >> 4;

  // A staging: thread t -> rows prow+64p (p=0..3), chunk q; pre-swizzled source col.
  const int prow = tid >> 2;                       // 0..63
  const int q = tid & 3;
  const int ascol = (q ^ ((prow >> 1) & 3)) * 8;
  const u16* xs[4];
#pragma unroll
  for (int p = 0; p < 4; ++p)
    xs[p] = xb + (size_t)(toks[p * 64 + prow] >> 1) * DIM + ascol;  // item -> token

  // B: thread t -> weight row br (=prow), f32 cols q*8..q*8+7 -> one 16B bf16 chunk.
  const int br = prow;
  const float* w1p = w1 + ((size_t)e * HID + n0 + br) * DIM + q * 8;
  const float* w3p = w3 + ((size_t)e * HID + n0 + br) * DIM + q * 8;
  const int bby = (br << 6) + ((q << 4) ^ (((br >> 1) & 3) << 4));

  float4 b1r[2][2], b3r[2][2];    // [set][chunk], statically indexed only
  f32x4 acc1[4][4] = {};
  f32x4 acc3[4][4] = {};

#define KCL(k) ((k) < DIM ? (k) : (DIM - 32))
#define G1_LOADB(set, k)                                  \
  {                                                       \
    b1r[set][0] = *(const float4*)(w1p + (k));            \
    b1r[set][1] = *(const float4*)(w1p + (k) + 4);        \
    b3r[set][0] = *(const float4*)(w3p + (k));            \
    b3r[set][1] = *(const float4*)(w3p + (k) + 4);        \
  }
#define G1_STGA(buf, k)                                   \
  {                                                       \
    char* aD = (char*)As[buf] + tid * 16;                 \
    async16(xs[0] + (k), aD);                             \
    async16(xs[1] + (k), aD + 4096);                      \
    async16(xs[2] + (k), aD + 8192);                      \
    async16(xs[3] + (k), aD + 12288);                     \
  }
#define G1_WRITEB(buf, set)                                   \
  {                                                           \
    cvst8(b1r[set][0], b1r[set][1], (char*)B1s[buf] + bby);   \
    cvst8(b3r[set][0], b3r[set][1], (char*)B3s[buf] + bby);   \
  }
#define G1_COMP(cb)                                                          \
  {                                                                          \
    bf16x8 a[4];                                                             \
    _Pragma("unroll") for (int m = 0; m < 4; ++m)                            \
        a[m] = *fragpB(As[cb], wrow + m * 16 + lr, kg);                      \
    _Pragma("unroll") for (int n = 0; n < 4; ++n) {                          \
      bf16x8 b1 = *fragpB(B1s[cb], n * 16 + lr, kg);                         \
      bf16x8 b3 = *fragpB(B3s[cb], n * 16 + lr, kg);                         \
      _Pragma("unroll") for (int m = 0; m < 4; ++m) {                        \
        acc1[m][n] = __builtin_amdgcn_mfma_f32_16x16x32_bf16(a[m], b1, acc1[m][n], 0, 0, 0); \
        acc3[m][n] = __builtin_amdgcn_mfma_f32_16x16x32_bf16(a[m], b3, acc3[m][n], 0, 0, 0); \
      }                                                                      \
    }                                                                        \
  }
// One pipelined iteration. Issue order pinned by sched_barrier(0) so the
// literal vmcnt(4) at the end drains exactly A_{i+1} (older) and keeps
// B_{i+2} (newer, 4 loads) in flight across the raw barrier.
#define G1_ITER(i, cb)                                               \
  {                                                                  \
    G1_STGA(cb ^ 1, KCL(32 * ((i) + 1)));                            \
    G1_WRITEB(cb ^ 1, cb ^ 1); /* B_{i+1} regs -> LDS */             \
    __builtin_amdgcn_sched_barrier(0);                               \
    G1_LOADB(cb, KCL(32 * ((i) + 2)));                               \
    __builtin_amdgcn_sched_barrier(0);                               \
    G1_COMP(cb);                                                     \
    asm volatile("s_waitcnt vmcnt(4) lgkmcnt(0)" ::: "memory");      \
    __builtin_amdgcn_sched_barrier(0);                               \
    __builtin_amdgcn_s_barrier();                                    \
    __builtin_amdgcn_sched_barrier(0);                               \
  }

  // prologue: B0 -> set0, A0 -> buf0, B1 -> set1; drain B0+A0; write B0 to LDS0.
  G1_LOADB(0, 0);
  __builtin_amdgcn_sched_barrier(0);
  G1_STGA(0, 0);
  __builtin_amdgcn_sched_barrier(0);
  G1_LOADB(1, 32);
  asm volatile("s_waitcnt vmcnt(4)" ::: "memory");   // drain B0(4)+A0(4); B1 stays
  __builtin_amdgcn_sched_barrier(0);
  G1_WRITEB(0, 0);
  asm volatile("s_waitcnt lgkmcnt(0)" ::: "memory");
  __builtin_amdgcn_sched_barrier(0);
  __builtin_amdgcn_s_barrier();
  __builtin_amdgcn_sched_barrier(0);

  for (int i = 0; i < 32; i += 2) {
    G1_ITER(i, 0);
    G1_ITER(i + 1, 1);
  }
#undef G1_ITER
#undef G1_COMP
#undef G1_WRITEB
#undef G1_STGA
#undef G1_LOADB
#undef KCL

#pragma unroll
  for (int m = 0; m < 4; ++m) {
#pragma unroll
    for (int r = 0; r < 4; ++r) {
      const int row = wrow + m * 16 + kg * 4 + r;
      if (m0 + row < cnt) {
        const int it = toks[row];
        u16* gp = G + (size_t)it * HID + n0 + lr;
#pragma unroll
        for (int n = 0; n < 4; ++n) {
          float v1 = acc1[m][n][r];
          float v3 = acc3[m][n][r];
          float s = v1 / (1.f + __expf(-v1)) * v3;
          gp[n * 16] = f2bf(s);
        }
      }
    }
  }
}

// GEMM2: out[item][d] = G[item][:] . w2t[e][d][:] — 128x64 tile, BK=64, dbuf 2-phase,
// both operands global_load_lds with R4 conflict-free swizzle.
__global__ __launch_bounds__(256, 3) void gemm2F(
    const u16* __restrict__ G, const u16* __restrict__ w2t,
    const int* __restrict__ counts, const int* __restrict__ lists,
    float* __restrict__ out) {
  __shared__ __align__(16) u16 As[2][128 * 64];  // 16 KB each
  __shared__ __align__(16) u16 Bs[2][64 * 64];   // 8 KB each
  __shared__ int toks[128];

  const int e = blockIdx.z;
  int cnt = counts[e];
  if ((unsigned)cnt > CAP) cnt = 0;
  const int m0 = blockIdx.y * 128;
  if (m0 >= cnt) return;
  const int n0 = blockIdx.x * 64;
  const int tid = threadIdx.x;

  if (tid < 128) {
    int r = m0 + tid;
    int it = lists[e * CAP + (r < cnt ? r : 0)];
    toks[tid] = ((unsigned)it < NITEM) ? it : 0;
  }
  __syncthreads();

  const int lane = tid & 63;
  const int wid = tid >> 6;
  const int wr = (wid >> 1) * 64;   // {0,64}
  const int wc = (wid & 1) * 32;    // {0,32}
  const int lr = lane & 15;
  const int kg = lane >> 4;

  const int srow = tid >> 3;                       // 0..31
  const int scol = ((tid & 7) ^ (srow & 7)) * 8;   // pre-swizzled source col (128B rows)

  const u16* as0 = G + (size_t)toks[srow] * HID + scol;
  const u16* as1 = G + (size_t)toks[32 + srow] * HID + scol;
  const u16* as2 = G + (size_t)toks[64 + srow] * HID + scol;
  const u16* as3 = G + (size_t)toks[96 + srow] * HID + scol;
  const u16* bs0 = w2t + ((size_t)e * DIM + n0 + srow) * HID + scol;
  const u16* bs1 = bs0 + (size_t)32 * HID;

  f32x4 acc[4][2] = {};

#define STG2(buf, k)                          \
  {                                           \
    char* aD = (char*)As[buf] + tid * 16;     \
    char* bD = (char*)Bs[buf] + tid * 16;     \
    async16(as0 + (k), aD);                   \
    async16(as1 + (k), aD + 4096);            \
    async16(as2 + (k), aD + 8192);            \
    async16(as3 + (k), aD + 12288);           \
    async16(bs0 + (k), bD);                   \
    async16(bs1 + (k), bD + 4096);            \
  }

  STG2(0, 0);
  __syncthreads();

  int cur = 0;
  for (int k0 = 0; k0 < HID; k0 += 64) {
    if (k0 + 64 < HID) STG2(cur ^ 1, k0 + 64);
    const u16* Ab = As[cur];
    const u16* Bb = Bs[cur];
#pragma unroll
    for (int kk = 0; kk < 2; ++kk) {
      const int ko = kk * 32 + kg * 8;
      bf16x8 a[4], b[2];
#pragma unroll
      for (int m = 0; m < 4; ++m) a[m] = *fragpA(Ab, wr + m * 16 + lr, ko);
#pragma unroll
      for (int n = 0; n < 2; ++n) b[n] = *fragpA(Bb, wc + n * 16 + lr, ko);
#pragma unroll
      for (int n = 0; n < 2; ++n)
#pragma unroll
        for (int m = 0; m < 4; ++m)
          acc[m][n] = __builtin_amdgcn_mfma_f32_16x16x32_bf16(a[m], b[n], acc[m][n], 0, 0, 0);
    }
    __syncthreads();
    cur ^= 1;
  }
#undef STG2

#pragma unroll
  for (int m = 0; m < 4; ++m) {
#pragma unroll
    for (int r = 0; r < 4; ++r) {
      const int row = wr + m * 16 + kg * 4 + r;
      if (m0 + row < cnt) {
        const int it = toks[row];
        float* op = out + (size_t)it * DIM + n0 + wc + lr;
#pragma unroll
        for (int n = 0; n < 2; ++n)
          op[n * 16] = acc[m][n][r];
      }
    }
  }
}

// ---------------- Path B (fallback, small workspace): round-2 kernels ----------------

__global__ __launch_bounds__(256, 2) void gemm1B(
    const float* __restrict__ x, const float* __restrict__ w1,
    const float* __restrict__ w3, const int* __restrict__ counts,
    const int* __restrict__ lists, u16* __restrict__ G) {
  __shared__ __align__(16) u16 As[128 * LDP];
  __shared__ __align__(16) u16 B1s[128 * LDP];
  __shared__ __align__(16) u16 B3s[128 * LDP];
  __shared__ int toks[128];

  const int e = blockIdx.z;
  int cnt = counts[e];
  if ((unsigned)cnt > CAP) cnt = 0;
  const int m0 = blockIdx.y * 128;
  if (m0 >= cnt) return;
  const int n0 = blockIdx.x * 128;
  const int tid = threadIdx.x;

  if (tid < 128) {
    int r = m0 + tid;
    int it = lists[e * CAP + (r < cnt ? r : 0)];
    toks[tid] = ((unsigned)it < NITEM) ? it : 0;
  }
  __syncthreads();

  const int lane = tid & 63;
  const int wr = ((tid >> 7) & 1) * 64;
  const int wc = ((tid >> 6) & 1) * 64;
  const int lr = lane & 15;
  const int kg = lane >> 4;
  const int arow = tid >> 3;
  const int c8 = (tid & 7) * 8;

  const float* xsrc[4];
#pragma unroll
  for (int p = 0; p < 4; ++p)
    xsrc[p] = x + (size_t)(toks[p * 32 + arow] >> 1) * DIM + c8;
  const float* w1p = w1 + ((size_t)e * HID + n0 + arow) * DIM + c8;
  const float* w3p = w3 + ((size_t)e * HID + n0 + arow) * DIM + c8;

  f32x4 acc1[4][4] = {};
  f32x4 acc3[4][4] = {};

  for (int k0 = 0; k0 < DIM; k0 += 64) {
#pragma unroll
    for (int p = 0; p < 4; ++p) {
      float4 v0 = *(const float4*)(xsrc[p] + k0);
      float4 v1 = *(const float4*)(xsrc[p] + k0 + 4);
      uint4 u;
      u.x = pk2(v0.x, v0.y); u.y = pk2(v0.z, v0.w);
      u.z = pk2(v1.x, v1.y); u.w = pk2(v1.z, v1.w);
      *(uint4*)&As[(p * 32 + arow) * LDP + c8] = u;
    }
#pragma unroll
    for (int p = 0; p < 4; ++p) {
      float4 v0 = *(const float4*)(w1p + (size_t)(p * 32) * DIM + k0);
      float4 v1 = *(const float4*)(w1p + (size_t)(p * 32) * DIM + k0 + 4);
      uint4 u;
      u.x = pk2(v0.x, v0.y); u.y = pk2(v0.z, v0.w);
      u.z = pk2(v1.x, v1.y); u.w = pk2(v1.z, v1.w);
      *(uint4*)&B1s[(p * 32 + arow) * LDP + c8] = u;
      v0 = *(const float4*)(w3p + (size_t)(p * 32) * DIM + k0);
      v1 = *(const float4*)(w3p + (size_t)(p * 32) * DIM + k0 + 4);
      u.x = pk2(v0.x, v0.y); u.y = pk2(v0.z, v0.w);
      u.z = pk2(v1.x, v1.y); u.w = pk2(v1.z, v1.w);
      *(uint4*)&B3s[(p * 32 + arow) * LDP + c8] = u;
    }
    __syncthreads();
#pragma unroll
    for (int kk = 0; kk < 2; ++kk) {
      const int ko = kk * 32 + kg * 8;
      bf16x8 a[4];
#pragma unroll
      for (int m = 0; m < 4; ++m)
        a[m] = *(const bf16x8*)&As[(wr + m * 16 + lr) * LDP + ko];
#pragma unroll
      for (int n = 0; n < 4; ++n) {
        bf16x8 b1 = *(const bf16x8*)&B1s[(wc + n * 16 + lr) * LDP + ko];
        bf16x8 b3 = *(const bf16x8*)&B3s[(wc + n * 16 + lr) * LDP + ko];
#pragma unroll
        for (int m = 0; m < 4; ++m) {
          acc1[m][n] = __builtin_amdgcn_mfma_f32_16x16x32_bf16(a[m], b1, acc1[m][n], 0, 0, 0);
          acc3[m][n] = __builtin_amdgcn_mfma_f32_16x16x32_bf16(a[m], b3, acc3[m][n], 0, 0, 0);
        }
      }
    }
    __syncthreads();
  }

#pragma unroll
  for (int m = 0; m < 4; ++m) {
#pragma unroll
    for (int r = 0; r < 4; ++r) {
      const int row = wr + m * 16 + kg * 4 + r;
      if (m0 + row < cnt) {
        const int it = toks[row];
        u16* gp = G + (size_t)it * HID + n0 + wc + lr;
#pragma unroll
        for (int n = 0; n < 4; ++n) {
          float v1 = acc1[m][n][r];
          float v3 = acc3[m][n][r];
          float s = v1 / (1.f + __expf(-v1)) * v3;
          gp[n * 16] = f2bf(s);
        }
      }
    }
  }
}

__global__ __launch_bounds__(256, 2) void gemm2B(
    const u16* __restrict__ G, const float* __restrict__ w2,
    const int* __restrict__ counts, const int* __restrict__ lists,
    float* __restrict__ out) {
  __shared__ __align__(16) u16 As[128 * LDP];
  __shared__ __align__(16) u16 Bs[128 * LDP];
  __shared__ int toks[128];

  const int e = blockIdx.z;
  int cnt = counts[e];
  if ((unsigned)cnt > CAP) cnt = 0;
  const int m0 = blockIdx.y * 128;
  if (m0 >= cnt) return;
  const int n0 = blockIdx.x * 128;
  const int tid = threadIdx.x;

  if (tid < 128) {
    int r = m0 + tid;
    int it = lists[e * CAP + (r < cnt ? r : 0)];
    toks[tid] = ((unsigned)it < NITEM) ? it : 0;
  }
  __syncthreads();

  const int lane = tid & 63;
  const int wr = ((tid >> 7) & 1) * 64;
  const int wc = ((tid >> 6) & 1) * 64;
  const int lr = lane & 15;
  const int kg = lane >> 4;
  const int arow = tid >> 3;
  const int c8 = (tid & 7) * 8;
  const int brow = tid >> 5;
  const int d4 = (tid & 31) * 4;

  const u16* asrc[4];
#pragma unroll
  for (int p = 0; p < 4; ++p)
    asrc[p] = G + (size_t)toks[p * 32 + arow] * HID + c8;
  const float* bsrc = w2 + ((size_t)e * HID) * DIM + n0 + d4;

  f32x4 acc[4][4] = {};

  for (int k0 = 0; k0 < HID; k0 += 64) {
#pragma unroll
    for (int p = 0; p < 4; ++p) {
      uint4 u = *(const uint4*)(asrc[p] + k0);
      *(uint4*)&As[(p * 32 + arow) * LDP + c8] = u;
    }
#pragma unroll
    for (int p = 0; p < 8; ++p) {
      const int hl = p * 8 + brow;
      float4 v = *(const float4*)(bsrc + (size_t)(k0 + hl) * DIM);
      Bs[(d4 + 0) * LDP + hl] = f2bf(v.x);
      Bs[(d4 + 1) * LDP + hl] = f2bf(v.y);
      Bs[(d4 + 2) * LDP + hl] = f2bf(v.z);
      Bs[(d4 + 3) * LDP + hl] = f2bf(v.w);
    }
    __syncthreads();
#pragma unroll
    for (int kk = 0; kk < 2; ++kk) {
      const int ko = kk * 32 + kg * 8;
      bf16x8 a[4];
#pragma unroll
      for (int m = 0; m < 4; ++m)
        a[m] = *(const bf16x8*)&As[(wr + m * 16 + lr) * LDP + ko];
#pragma unroll
      for (int n = 0; n < 4; ++n) {
        bf16x8 b = *(const bf16x8*)&Bs[(wc + n * 16 + lr) * LDP + ko];
#pragma unroll
        for (int m = 0; m < 4; ++m)
          acc[m][n] = __builtin_amdgcn_mfma_f32_16x16x32_bf16(a[m], b, acc[m][n], 0, 0, 0);
      }
    }
    __syncthreads();
  }

#pragma unroll
  for (int m = 0; m < 4; ++m) {
#pragma unroll
    for (int r = 0; r < 4; ++r) {
      const int row = wr + m * 16 + kg * 4 + r;
      if (m0 + row < cnt) {
        const int it = toks[row];
        float* op = out + (size_t)it * DIM + n0 + wc + lr;
#pragma unroll
        for (int n = 0; n < 4; ++n)
          op[n * 16] = acc[m][n][r];
      }
    }
  }
}

extern "C" void kernel_launch(void* const* d_in, const int* in_sizes, int n_in,
                              void* d_out, int out_size, void* d_ws, size_t ws_size,
                              hipStream_t stream) {
  (void)in_sizes; (void)n_in; (void)out_size;
  const float* x  = (const float*)d_in[0];
  const int*   ei = (const int*)d_in[1];
  const float* w1 = (const float*)d_in[2];
  const float* w2 = (const float*)d_in[3];
  const float* w3 = (const float*)d_in[4];
  float* out = (float*)d_out;

  char* ws = (char*)d_ws;

  // Path A layout: G | xb | w2t | counts | lists  (~73.5 MB)
  const size_t oG = 0;
  const size_t oXB = 23068672u;
  const size_t oW2T = oXB + 4194304u;
  const size_t oCNT = oW2T + 46137344u;
  const size_t oLST = oCNT + 64u;
  const size_t needA = oLST + 131072u;

  if (ws_size >= needA) {
    u16* G      = (u16*)(ws + oG);
    u16* xb     = (u16*)(ws + oXB);
    u16* w2t    = (u16*)(ws + oW2T);
    int* counts = (int*)(ws + oCNT);
    int* lists  = (int*)(ws + oLST);

    zero8<<<1, 64, 0, stream>>>(counts);
    bucket<<<NITEM / 256, 256, 0, stream>>>(ei, counts, lists);
    cvt8<<<(NTOK * DIM / 8) / 256, 256, 0, stream>>>(x, xb, NTOK * DIM / 8);
    gemm1H<<<dim3(HID / 64, CAP / 256, NEXP), 256, 0, stream>>>(xb, w1, w3, counts, lists, G);
    tw2<<<dim3(DIM / 64, HID / 64, NEXP), 256, 0, stream>>>(w2, w2t);
    gemm2F<<<dim3(DIM / 64, CAP / 128, NEXP), 256, 0, stream>>>(G, w2t, counts, lists, out);
  } else {
    // fallback: compact workspace, on-the-fly conversion (round-2 path)
    u16* G      = (u16*)ws;
    int* counts = (int*)(ws + 23068672u);
    int* lists  = (int*)(ws + 23068736u);

    zero8<<<1, 64, 0, stream>>>(counts);
    bucket<<<NITEM / 256, 256, 0, stream>>>(ei, counts, lists);
    gemm1B<<<dim3(HID / 128, CAP / 128, NEXP), 256, 0, stream>>>(x, w1, w3, counts, lists, G);
    gemm2B<<<dim3(DIM / 128, CAP / 128, NEXP), 256, 0, stream>>>(G, w2, counts, lists, out);
  }
}